// Round 4
// baseline (370.830 us; speedup 1.0000x reference)
//
#include <hip/hip_runtime.h>
#include <hip/hip_bf16.h>
#include <math.h>

#define TT 4096
#define EE 8
#define DD 1024
#define HH 1024
#define CAP 4096

typedef __attribute__((ext_vector_type(8))) short bf16x8;
typedef __attribute__((ext_vector_type(4))) float f32x4;

// ---------------- workspace layout (bytes) ----------------
static const size_t OFF_XB     = 0;                         // bf16 [4096][1024]  8 MB
static const size_t OFF_W1T    = 8u * 1024 * 1024;          // bf16 [8][H][D]    16 MB
static const size_t OFF_W2T    = 24u * 1024 * 1024;         // bf16 [8][D][H]    16 MB
static const size_t OFF_ABUF   = 40u * 1024 * 1024;         // bf16 [8192][1024] 16 MB
static const size_t OFF_ROWMAP = 88u * 1024 * 1024;         // int  [8][4096]   128 KB
static const size_t OFF_GATES  = OFF_ROWMAP + 8 * CAP * 4;  // f32  [8192]       32 KB
static const size_t OFF_COUNTS = OFF_GATES + 8192 * 4;      // int  [8]
static const size_t OFF_PICKS  = OFF_COUNTS + 256;          // int  [4096]       16 KB

// ---------------- prep: fused weight transpose (blocks 0..4095) + gating (4096..4351) ----
__global__ __launch_bounds__(256) void prep_kernel(
    const float* __restrict__ x, const float* __restrict__ wg,
    const float* __restrict__ w1, const float* __restrict__ w2,
    __hip_bfloat16* __restrict__ xb,
    __hip_bfloat16* __restrict__ w1t, __hip_bfloat16* __restrict__ w2t,
    int* __restrict__ picks, float* __restrict__ gates)
{
    __shared__ float tl[64][65];
    const int bid = blockIdx.x;
    const int tid = threadIdx.x;

    if (bid < 4096) {
        // ---- transpose path: 16 matrices x 256 tiles of 64x64 ----
        const int mat = bid >> 8;
        const int tt = bid & 255;
        const int R = (tt >> 4) * 64;   // src row base (k)
        const int C = (tt & 15) * 64;   // src col base (n)
        const float* src = (mat < EE ? w1 : w2) + (size_t)(mat & 7) * DD * HH;
        __hip_bfloat16* dst = (mat < EE ? w1t : w2t) + (size_t)(mat & 7) * DD * HH;

        const int lrow = tid >> 4;
        const int c4 = tid & 15;
#pragma unroll
        for (int i = 0; i < 4; ++i) {
            const int r = lrow + i * 16;
            float4 v = *(const float4*)(src + (size_t)(R + r) * 1024 + C + c4 * 4);
            tl[r][c4 * 4 + 0] = v.x;
            tl[r][c4 * 4 + 1] = v.y;
            tl[r][c4 * 4 + 2] = v.z;
            tl[r][c4 * 4 + 3] = v.w;
        }
        __syncthreads();
        const int seg = tid & 7;
        const int orow0 = tid >> 3;
#pragma unroll
        for (int p = 0; p < 2; ++p) {
            const int orow = orow0 + p * 32;
            unsigned short u[8];
#pragma unroll
            for (int j = 0; j < 8; ++j) {
                __hip_bfloat16 h = __float2bfloat16(tl[seg * 8 + j][orow]);
                u[j] = *(unsigned short*)&h;
            }
            *(ushort4*)(dst + (size_t)(C + orow) * 1024 + R + seg * 8)     = (ushort4){u[0], u[1], u[2], u[3]};
            *(ushort4*)(dst + (size_t)(C + orow) * 1024 + R + seg * 8 + 4) = (ushort4){u[4], u[5], u[6], u[7]};
        }
        return;
    }

    // ---- gate path ----
    const int lane = tid & 63;
    const int wave = tid >> 6;
    const int tbase = (bid - 4096) * 16 + wave * 4;

    for (int i = 0; i < 4; ++i) {
        const int t = tbase + i;
        const float4* xr = (const float4*)(x + (size_t)t * DD);
        ushort4* xbr = (ushort4*)(xb + (size_t)t * DD);

        float acc[EE];
#pragma unroll
        for (int e = 0; e < EE; ++e) acc[e] = 0.f;

#pragma unroll
        for (int c = 0; c < 4; ++c) {
            const int v4 = lane + 64 * c;
            float4 xv = xr[v4];
            __hip_bfloat16 h0 = __float2bfloat16(xv.x);
            __hip_bfloat16 h1 = __float2bfloat16(xv.y);
            __hip_bfloat16 h2 = __float2bfloat16(xv.z);
            __hip_bfloat16 h3 = __float2bfloat16(xv.w);
            ushort4 s;
            s.x = *(unsigned short*)&h0; s.y = *(unsigned short*)&h1;
            s.z = *(unsigned short*)&h2; s.w = *(unsigned short*)&h3;
            xbr[v4] = s;
            const float4* wrow = (const float4*)(wg + (size_t)(4 * v4) * EE);
            const float xs[4] = {xv.x, xv.y, xv.z, xv.w};
#pragma unroll
            for (int q = 0; q < 4; ++q) {
                float4 w0 = wrow[q * 2];
                float4 w1v = wrow[q * 2 + 1];
                acc[0] = fmaf(xs[q], w0.x, acc[0]);
                acc[1] = fmaf(xs[q], w0.y, acc[1]);
                acc[2] = fmaf(xs[q], w0.z, acc[2]);
                acc[3] = fmaf(xs[q], w0.w, acc[3]);
                acc[4] = fmaf(xs[q], w1v.x, acc[4]);
                acc[5] = fmaf(xs[q], w1v.y, acc[5]);
                acc[6] = fmaf(xs[q], w1v.z, acc[6]);
                acc[7] = fmaf(xs[q], w1v.w, acc[7]);
            }
        }
#pragma unroll
        for (int off = 32; off > 0; off >>= 1) {
#pragma unroll
            for (int e = 0; e < EE; ++e) acc[e] += __shfl_xor(acc[e], off, 64);
        }
        if (lane == 0) {
            float mx = acc[0];
#pragma unroll
            for (int e = 1; e < EE; ++e) mx = fmaxf(mx, acc[e]);
            float p[EE];
            float s = 0.f;
#pragma unroll
            for (int e = 0; e < EE; ++e) { p[e] = expf(acc[e] - mx); s += p[e]; }
            int i0 = 0;
#pragma unroll
            for (int e = 1; e < EE; ++e) if (acc[e] > acc[i0]) i0 = e;
            int i1 = (i0 == 0) ? 1 : 0;
#pragma unroll
            for (int e = 0; e < EE; ++e) {
                if (e != i0 && acc[e] > acc[i1]) i1 = e;
            }
            float v0 = p[i0] / s, v1 = p[i1] / s;
            float den = v0 + v1 + 1e-6f;
            gates[t * 2 + 0] = v0 / den;
            gates[t * 2 + 1] = v1 / den;
            picks[t] = i0 | (i1 << 4);
        }
    }
}

// ---------------- bucket build (deterministic, no global atomics) ----------------
__global__ __launch_bounds__(256) void bucket_build(
    const int* __restrict__ picks, int* __restrict__ rowmap, int* __restrict__ counts)
{
    const int e = blockIdx.x;
    const int tid = threadIdx.x;
    const int lane = tid & 63;
    const int wave = tid >> 6;
    __shared__ int wsum[4];

    int runtot = 0;
    for (int tb = 0; tb < TT; tb += 256) {
        const int t = tb + tid;
        const int p = picks[t];
        const int m0 = ((p & 15) == e) ? 1 : 0;
        const int m1 = (((p >> 4) & 15) == e) ? 1 : 0;
        const int c = m0 + m1;
        int incl = c;
#pragma unroll
        for (int off = 1; off < 64; off <<= 1) {
            int v = __shfl_up(incl, off, 64);
            if (lane >= off) incl += v;
        }
        if (lane == 63) wsum[wave] = incl;
        __syncthreads();
        int wbase = 0;
#pragma unroll
        for (int w = 0; w < 4; ++w) wbase += (w < wave) ? wsum[w] : 0;
        int slot = runtot + wbase + incl - c;
        if (m0) { rowmap[e * CAP + slot] = t * 2; slot += 1; }
        if (m1) { rowmap[e * CAP + slot] = t * 2 + 1; }
        runtot += wsum[0] + wsum[1] + wsum[2] + wsum[3];
        __syncthreads();
    }
    if (tid == 0) counts[e] = runtot;
}

// ---------------- grouped GEMM, barrier-free: 64x64 tile per 1-wave block, no LDS --------
// Both MFMA operands load DIRECTLY global->VGPR (A is [m][k] k-contig, B is [n][k]
// k-contig; lane needs a contiguous 16B chunk = one global_load_dwordx4, 16 full 64B
// lines per instruction). No __syncthreads, no vmcnt(0) drain; compiler schedules
// fine-grained vmcnt across the 2-stage register pipeline. Grid ~2048 live 1-wave
// blocks = 8 waves/CU of independent pipelines.
// LAYER==1: out = gelu(C + b1) -> bf16 abuf[(t,k) slot]
// LAYER==2: out = (C + b2) * gate -> atomicAdd into y[t] (2 addends/addr, order-safe)
template <int LAYER>
__global__ __launch_bounds__(64) void moe_gemm(
    const __hip_bfloat16* __restrict__ Abase,
    const __hip_bfloat16* __restrict__ Bbase,   // [E][N=1024][K=1024], K contiguous
    const float* __restrict__ bias,             // [E][1024]
    const int* __restrict__ rowmap,
    const int* __restrict__ counts,
    const float* __restrict__ gates,
    void* __restrict__ OutP)
{
    const int e = blockIdx.z;
    const int cnt = counts[e];
    const int m0 = blockIdx.y * 64;
    if (m0 >= cnt) return;
    const int n0 = blockIdx.x * 64;
    const int lane = threadIdx.x;
    const int lrow = lane & 15;
    const int quad = lane >> 4;

    const __hip_bfloat16* Bexp = Bbase + (size_t)e * DD * HH;
    const __hip_bfloat16* ap[4];
    const __hip_bfloat16* bp[4];
#pragma unroll
    for (int i = 0; i < 4; ++i) {
        const int gm = m0 + i * 16 + lrow;
        const int ent = rowmap[e * CAP + (gm < cnt ? gm : 0)];
        const size_t src = (size_t)(LAYER == 1 ? (ent >> 1) : ent);
        ap[i] = Abase + src * DD + quad * 8;
        bp[i] = Bexp + (size_t)(n0 + i * 16 + lrow) * DD + quad * 8;
    }

    f32x4 acc[4][4];
#pragma unroll
    for (int i = 0; i < 4; ++i)
#pragma unroll
        for (int j = 0; j < 4; ++j) acc[i][j] = (f32x4){0.f, 0.f, 0.f, 0.f};

    bf16x8 aF[2][4], bF[2][4];
#define LOADF(S, KO)                                                       \
    {                                                                      \
        _Pragma("unroll") for (int i = 0; i < 4; ++i) {                    \
            aF[S][i] = *(const bf16x8*)(ap[i] + (KO));                     \
            bF[S][i] = *(const bf16x8*)(bp[i] + (KO));                     \
        }                                                                  \
    }
#define MM(S)                                                              \
    {                                                                      \
        _Pragma("unroll") for (int mi = 0; mi < 4; ++mi)                   \
            _Pragma("unroll") for (int ni = 0; ni < 4; ++ni)               \
                acc[mi][ni] = __builtin_amdgcn_mfma_f32_16x16x32_bf16(     \
                    aF[S][mi], bF[S][ni], acc[mi][ni], 0, 0, 0);           \
    }

    LOADF(0, 0);
#pragma unroll 4
    for (int it = 0; it < 16; ++it) {
        LOADF(1, 64 * it + 32);
        MM(0);
        // it==15 loads k=1024: 128B past row end, still inside d_ws, never consumed
        LOADF(0, 64 * it + 64);
        MM(1);
    }
#undef LOADF
#undef MM

    // epilogue: C/D layout col = lane&15, row = quad*4 + reg (m89/m91 verified)
    if (LAYER == 1) {
        __hip_bfloat16* abuf = (__hip_bfloat16*)OutP;
#pragma unroll
        for (int mi = 0; mi < 4; ++mi) {
#pragma unroll
            for (int r = 0; r < 4; ++r) {
                const int gm = m0 + mi * 16 + quad * 4 + r;
                if (gm < cnt) {
                    const int ent = rowmap[e * CAP + gm];
                    __hip_bfloat16* orow = abuf + (size_t)ent * HH + n0 + lrow;
#pragma unroll
                    for (int ni = 0; ni < 4; ++ni) {
                        float v = acc[mi][ni][r] + bias[e * HH + n0 + ni * 16 + lrow];
                        v = 0.5f * v * (1.f + erff(v * 0.70710678118654752f));  // exact GELU
                        orow[ni * 16] = __float2bfloat16(v);
                    }
                }
            }
        }
    } else {
        float* y = (float*)OutP;
#pragma unroll
        for (int mi = 0; mi < 4; ++mi) {
#pragma unroll
            for (int r = 0; r < 4; ++r) {
                const int gm = m0 + mi * 16 + quad * 4 + r;
                if (gm < cnt) {
                    const int ent = rowmap[e * CAP + gm];
                    const float g = gates[ent];
                    const int t = ent >> 1;
                    float* yrow = y + (size_t)t * DD + n0 + lrow;
#pragma unroll
                    for (int ni = 0; ni < 4; ++ni) {
                        float v = acc[mi][ni][r] + bias[e * DD + n0 + ni * 16 + lrow];
                        atomicAdd(yrow + ni * 16, v * g);
                    }
                }
            }
        }
    }
}

extern "C" void kernel_launch(void* const* d_in, const int* in_sizes, int n_in,
                              void* d_out, int out_size, void* d_ws, size_t ws_size,
                              hipStream_t stream)
{
    const float* x  = (const float*)d_in[0];
    const float* w1 = (const float*)d_in[1];
    const float* b1 = (const float*)d_in[2];
    const float* w2 = (const float*)d_in[3];
    const float* b2 = (const float*)d_in[4];
    const float* wg = (const float*)d_in[5];
    float* y = (float*)d_out;

    char* ws = (char*)d_ws;
    __hip_bfloat16* xb   = (__hip_bfloat16*)(ws + OFF_XB);
    __hip_bfloat16* w1t  = (__hip_bfloat16*)(ws + OFF_W1T);
    __hip_bfloat16* w2t  = (__hip_bfloat16*)(ws + OFF_W2T);
    __hip_bfloat16* abuf = (__hip_bfloat16*)(ws + OFF_ABUF);
    int*   rowmap = (int*)(ws + OFF_ROWMAP);
    float* gates  = (float*)(ws + OFF_GATES);
    int*   counts = (int*)(ws + OFF_COUNTS);
    int*   picks  = (int*)(ws + OFF_PICKS);

    hipMemsetAsync(y, 0, (size_t)TT * DD * sizeof(float), stream);
    prep_kernel<<<4096 + 256, 256, 0, stream>>>(x, wg, w1, w2, xb, w1t, w2t, picks, gates);
    bucket_build<<<EE, 256, 0, stream>>>(picks, rowmap, counts);
    moe_gemm<1><<<dim3(HH / 64, CAP / 64, EE), 64, 0, stream>>>(
        xb, w1t, b1, rowmap, counts, gates, (void*)abuf);
    moe_gemm<2><<<dim3(DD / 64, CAP / 64, EE), 64, 0, stream>>>(
        abuf, w2t, b2, rowmap, counts, gates, (void*)y);
}

// Round 5
// 274.601 us; speedup vs baseline: 1.3504x; 1.3504x over previous
//
#include <hip/hip_runtime.h>
#include <hip/hip_bf16.h>
#include <math.h>

#define TT 4096
#define EE 8
#define DD 1024
#define HH 1024
#define CAP 4096

typedef __attribute__((ext_vector_type(8))) short bf16x8;
typedef __attribute__((ext_vector_type(4))) float f32x4;

// async global->LDS, 16B per lane; LDS dest is wave-uniform base + lane*16
#define GLL16(gp, lp)                                                                   \
    __builtin_amdgcn_global_load_lds((__attribute__((address_space(1))) void*)(gp),     \
                                     (__attribute__((address_space(3))) void*)(lp),     \
                                     16, 0, 0)

// ---------------- workspace layout (bytes) ----------------
static const size_t OFF_XB     = 0;                         // bf16 [4096][1024]  8 MB
static const size_t OFF_W1T    = 8u * 1024 * 1024;          // bf16 [8][H][D]    16 MB
static const size_t OFF_W2T    = 24u * 1024 * 1024;         // bf16 [8][D][H]    16 MB
static const size_t OFF_ABUF   = 40u * 1024 * 1024;         // bf16 [8192][1024] 16 MB
static const size_t OFF_ROWMAP = 88u * 1024 * 1024;         // int  [8][4096]   128 KB
static const size_t OFF_GATES  = OFF_ROWMAP + 8 * CAP * 4;  // f32  [8192]       32 KB
static const size_t OFF_COUNTS = OFF_GATES + 8192 * 4;      // int  [8]
static const size_t OFF_PICKS  = OFF_COUNTS + 256;          // int  [4096]       16 KB

// ---------------- prep: fused weight transpose (blocks 0..4095) + gating (4096..4351) ----
__global__ __launch_bounds__(256) void prep_kernel(
    const float* __restrict__ x, const float* __restrict__ wg,
    const float* __restrict__ w1, const float* __restrict__ w2,
    __hip_bfloat16* __restrict__ xb,
    __hip_bfloat16* __restrict__ w1t, __hip_bfloat16* __restrict__ w2t,
    int* __restrict__ picks, float* __restrict__ gates)
{
    __shared__ float tl[64][65];
    const int bid = blockIdx.x;
    const int tid = threadIdx.x;

    if (bid < 4096) {
        // ---- transpose path: 16 matrices x 256 tiles of 64x64 ----
        const int mat = bid >> 8;
        const int tt = bid & 255;
        const int R = (tt >> 4) * 64;   // src row base (k)
        const int C = (tt & 15) * 64;   // src col base (n)
        const float* src = (mat < EE ? w1 : w2) + (size_t)(mat & 7) * DD * HH;
        __hip_bfloat16* dst = (mat < EE ? w1t : w2t) + (size_t)(mat & 7) * DD * HH;

        const int lrow = tid >> 4;
        const int c4 = tid & 15;
#pragma unroll
        for (int i = 0; i < 4; ++i) {
            const int r = lrow + i * 16;
            float4 v = *(const float4*)(src + (size_t)(R + r) * 1024 + C + c4 * 4);
            tl[r][c4 * 4 + 0] = v.x;
            tl[r][c4 * 4 + 1] = v.y;
            tl[r][c4 * 4 + 2] = v.z;
            tl[r][c4 * 4 + 3] = v.w;
        }
        __syncthreads();
        const int seg = tid & 7;
        const int orow0 = tid >> 3;
#pragma unroll
        for (int p = 0; p < 2; ++p) {
            const int orow = orow0 + p * 32;
            unsigned short u[8];
#pragma unroll
            for (int j = 0; j < 8; ++j) {
                __hip_bfloat16 h = __float2bfloat16(tl[seg * 8 + j][orow]);
                u[j] = *(unsigned short*)&h;
            }
            *(ushort4*)(dst + (size_t)(C + orow) * 1024 + R + seg * 8)     = (ushort4){u[0], u[1], u[2], u[3]};
            *(ushort4*)(dst + (size_t)(C + orow) * 1024 + R + seg * 8 + 4) = (ushort4){u[4], u[5], u[6], u[7]};
        }
        return;
    }

    // ---- gate path ----
    const int lane = tid & 63;
    const int wave = tid >> 6;
    const int tbase = (bid - 4096) * 16 + wave * 4;

    for (int i = 0; i < 4; ++i) {
        const int t = tbase + i;
        const float4* xr = (const float4*)(x + (size_t)t * DD);
        ushort4* xbr = (ushort4*)(xb + (size_t)t * DD);

        float acc[EE];
#pragma unroll
        for (int e = 0; e < EE; ++e) acc[e] = 0.f;

#pragma unroll
        for (int c = 0; c < 4; ++c) {
            const int v4 = lane + 64 * c;
            float4 xv = xr[v4];
            __hip_bfloat16 h0 = __float2bfloat16(xv.x);
            __hip_bfloat16 h1 = __float2bfloat16(xv.y);
            __hip_bfloat16 h2 = __float2bfloat16(xv.z);
            __hip_bfloat16 h3 = __float2bfloat16(xv.w);
            ushort4 s;
            s.x = *(unsigned short*)&h0; s.y = *(unsigned short*)&h1;
            s.z = *(unsigned short*)&h2; s.w = *(unsigned short*)&h3;
            xbr[v4] = s;
            const float4* wrow = (const float4*)(wg + (size_t)(4 * v4) * EE);
            const float xs[4] = {xv.x, xv.y, xv.z, xv.w};
#pragma unroll
            for (int q = 0; q < 4; ++q) {
                float4 w0 = wrow[q * 2];
                float4 w1v = wrow[q * 2 + 1];
                acc[0] = fmaf(xs[q], w0.x, acc[0]);
                acc[1] = fmaf(xs[q], w0.y, acc[1]);
                acc[2] = fmaf(xs[q], w0.z, acc[2]);
                acc[3] = fmaf(xs[q], w0.w, acc[3]);
                acc[4] = fmaf(xs[q], w1v.x, acc[4]);
                acc[5] = fmaf(xs[q], w1v.y, acc[5]);
                acc[6] = fmaf(xs[q], w1v.z, acc[6]);
                acc[7] = fmaf(xs[q], w1v.w, acc[7]);
            }
        }
#pragma unroll
        for (int off = 32; off > 0; off >>= 1) {
#pragma unroll
            for (int e = 0; e < EE; ++e) acc[e] += __shfl_xor(acc[e], off, 64);
        }
        if (lane == 0) {
            float mx = acc[0];
#pragma unroll
            for (int e = 1; e < EE; ++e) mx = fmaxf(mx, acc[e]);
            float p[EE];
            float s = 0.f;
#pragma unroll
            for (int e = 0; e < EE; ++e) { p[e] = expf(acc[e] - mx); s += p[e]; }
            int i0 = 0;
#pragma unroll
            for (int e = 1; e < EE; ++e) if (acc[e] > acc[i0]) i0 = e;
            int i1 = (i0 == 0) ? 1 : 0;
#pragma unroll
            for (int e = 0; e < EE; ++e) {
                if (e != i0 && acc[e] > acc[i1]) i1 = e;
            }
            float v0 = p[i0] / s, v1 = p[i1] / s;
            float den = v0 + v1 + 1e-6f;
            gates[t * 2 + 0] = v0 / den;
            gates[t * 2 + 1] = v1 / den;
            picks[t] = i0 | (i1 << 4);
        }
    }
}

// ---------------- bucket build (deterministic, no global atomics) ----------------
__global__ __launch_bounds__(256) void bucket_build(
    const int* __restrict__ picks, int* __restrict__ rowmap, int* __restrict__ counts)
{
    const int e = blockIdx.x;
    const int tid = threadIdx.x;
    const int lane = tid & 63;
    const int wave = tid >> 6;
    __shared__ int wsum[4];

    int runtot = 0;
    for (int tb = 0; tb < TT; tb += 256) {
        const int t = tb + tid;
        const int p = picks[t];
        const int m0 = ((p & 15) == e) ? 1 : 0;
        const int m1 = (((p >> 4) & 15) == e) ? 1 : 0;
        const int c = m0 + m1;
        int incl = c;
#pragma unroll
        for (int off = 1; off < 64; off <<= 1) {
            int v = __shfl_up(incl, off, 64);
            if (lane >= off) incl += v;
        }
        if (lane == 63) wsum[wave] = incl;
        __syncthreads();
        int wbase = 0;
#pragma unroll
        for (int w = 0; w < 4; ++w) wbase += (w < wave) ? wsum[w] : 0;
        int slot = runtot + wbase + incl - c;
        if (m0) { rowmap[e * CAP + slot] = t * 2; slot += 1; }
        if (m1) { rowmap[e * CAP + slot] = t * 2 + 1; }
        runtot += wsum[0] + wsum[1] + wsum[2] + wsum[3];
        __syncthreads();
    }
    if (tid == 0) counts[e] = runtot;
}

// ---------------- grouped GEMM: 128x128 tile, BK=32, DOUBLE-BUFFERED LDS ----------------
// Round-2 proven structure + software pipeline: issue loads(kt+1) -> compute(kt) ->
// barrier. The ~600cyc compute phase overlaps the global->LDS latency, so the
// vmcnt drain at the barrier waits only the residue (round 2 paid it in full:
// load->barrier->compute put the whole latency on the critical path at 2 blocks/CU).
// LAYER==1: out = gelu(C + b1) -> bf16 abuf[(t,k) slot]
// LAYER==2: out = (C + b2) * gate -> atomicAdd into y (2 commutative addends/addr)
template <int LAYER>
__global__ __launch_bounds__(256) void moe_gemm(
    const __hip_bfloat16* __restrict__ Abase,
    const __hip_bfloat16* __restrict__ Bbase,   // [E][N=1024][K=1024], K contiguous
    const float* __restrict__ bias,             // [E][1024]
    const int* __restrict__ rowmap,
    const int* __restrict__ counts,
    const float* __restrict__ gates,
    void* __restrict__ OutP)
{
    const int e = blockIdx.z;
    const int cnt = counts[e];
    const int m0 = blockIdx.y * 128;
    if (m0 >= cnt) return;
    const int n0 = blockIdx.x * 128;
    const int tid = threadIdx.x;
    const int lane = tid & 63;
    const int wave = tid >> 6;
    const int wm = (wave >> 1) * 64;   // wave's 64x64 quadrant
    const int wn = (wave & 1) * 64;
    const int lrow = lane & 15;
    const int quad = lane >> 4;

    __shared__ __hip_bfloat16 As[2][128 * 32];   // 16 KB (double-buffered)
    __shared__ __hip_bfloat16 Bs[2][128 * 32];   // 16 KB

    const int ar0 = m0 + (tid >> 2);
    const int ar1 = ar0 + 64;
    const int e0 = rowmap[e * CAP + (ar0 < cnt ? ar0 : 0)];
    const int e1 = rowmap[e * CAP + (ar1 < cnt ? ar1 : 0)];
    const size_t src0 = (size_t)(LAYER == 1 ? (e0 >> 1) : e0);
    const size_t src1 = (size_t)(LAYER == 1 ? (e1 >> 1) : e1);
    const __hip_bfloat16* gA0 = Abase + src0 * DD + (tid & 3) * 8;
    const __hip_bfloat16* gA1 = Abase + src1 * DD + (tid & 3) * 8;
    const __hip_bfloat16* Bexp = Bbase + (size_t)e * DD * HH;
    const __hip_bfloat16* gB0 = Bexp + (size_t)(n0 + (tid >> 2)) * DD + (tid & 3) * 8;
    const __hip_bfloat16* gB1 = gB0 + (size_t)64 * DD;

    f32x4 acc[4][4];
#pragma unroll
    for (int i = 0; i < 4; ++i)
#pragma unroll
        for (int j = 0; j < 4; ++j) acc[i][j] = (f32x4){0.f, 0.f, 0.f, 0.f};

#define STAGE(BUF, KO)                                              \
    {                                                               \
        char* lA = (char*)&As[BUF][0] + wave * 1024;                \
        char* lB = (char*)&Bs[BUF][0] + wave * 1024;                \
        GLL16(gA0 + (KO), lA);                                      \
        GLL16(gA1 + (KO), lA + 4096);                               \
        GLL16(gB0 + (KO), lB);                                      \
        GLL16(gB1 + (KO), lB + 4096);                               \
    }

    STAGE(0, 0);
    __syncthreads();   // drain prologue load (paid once)

    for (int kt = 0; kt < DD / 32; ++kt) {
        const int cur = kt & 1;
        if (kt < DD / 32 - 1) STAGE(cur ^ 1, (kt + 1) * 32);   // prefetch next tile

        const bf16x8* Av = (const bf16x8*)&As[cur][0];
        const bf16x8* Bv = (const bf16x8*)&Bs[cur][0];
        bf16x8 af[4], bfr[4];
#pragma unroll
        for (int i = 0; i < 4; ++i) {
            af[i]  = Av[(wm + i * 16 + lrow) * 4 + quad];   // A[m][k0+quad*8 ..+7]
            bfr[i] = Bv[(wn + i * 16 + lrow) * 4 + quad];   // B fragment from [n][k] LDS
        }
#pragma unroll
        for (int mi = 0; mi < 4; ++mi)
#pragma unroll
            for (int ni = 0; ni < 4; ++ni)
                acc[mi][ni] = __builtin_amdgcn_mfma_f32_16x16x32_bf16(
                    af[mi], bfr[ni], acc[mi][ni], 0, 0, 0);
        __syncthreads();   // drain overlaps the compute above; protects cur^1 writes
    }
#undef STAGE

    // epilogue: C/D layout col = lane&15, row = quad*4 + reg (m89/m91 verified)
    if (LAYER == 1) {
        __hip_bfloat16* abuf = (__hip_bfloat16*)OutP;
#pragma unroll
        for (int mi = 0; mi < 4; ++mi) {
#pragma unroll
            for (int r = 0; r < 4; ++r) {
                const int mrow = wm + mi * 16 + quad * 4 + r;
                const int gm = m0 + mrow;
                if (gm < cnt) {
                    const int ent = rowmap[e * CAP + gm];
                    __hip_bfloat16* orow = abuf + (size_t)ent * HH + n0 + wn + lrow;
#pragma unroll
                    for (int ni = 0; ni < 4; ++ni) {
                        float v = acc[mi][ni][r] + bias[e * HH + n0 + wn + ni * 16 + lrow];
                        v = 0.5f * v * (1.f + erff(v * 0.70710678118654752f));  // exact GELU
                        orow[ni * 16] = __float2bfloat16(v);
                    }
                }
            }
        }
    } else {
        float* y = (float*)OutP;
#pragma unroll
        for (int mi = 0; mi < 4; ++mi) {
#pragma unroll
            for (int r = 0; r < 4; ++r) {
                const int mrow = wm + mi * 16 + quad * 4 + r;
                const int gm = m0 + mrow;
                if (gm < cnt) {
                    const int ent = rowmap[e * CAP + gm];
                    const float g = gates[ent];
                    const int t = ent >> 1;
                    float* yrow = y + (size_t)t * DD + n0 + wn + lrow;
#pragma unroll
                    for (int ni = 0; ni < 4; ++ni) {
                        float v = acc[mi][ni][r] + bias[e * DD + n0 + wn + ni * 16 + lrow];
                        atomicAdd(yrow + ni * 16, v * g);
                    }
                }
            }
        }
    }
}

extern "C" void kernel_launch(void* const* d_in, const int* in_sizes, int n_in,
                              void* d_out, int out_size, void* d_ws, size_t ws_size,
                              hipStream_t stream)
{
    const float* x  = (const float*)d_in[0];
    const float* w1 = (const float*)d_in[1];
    const float* b1 = (const float*)d_in[2];
    const float* w2 = (const float*)d_in[3];
    const float* b2 = (const float*)d_in[4];
    const float* wg = (const float*)d_in[5];
    float* y = (float*)d_out;

    char* ws = (char*)d_ws;
    __hip_bfloat16* xb   = (__hip_bfloat16*)(ws + OFF_XB);
    __hip_bfloat16* w1t  = (__hip_bfloat16*)(ws + OFF_W1T);
    __hip_bfloat16* w2t  = (__hip_bfloat16*)(ws + OFF_W2T);
    __hip_bfloat16* abuf = (__hip_bfloat16*)(ws + OFF_ABUF);
    int*   rowmap = (int*)(ws + OFF_ROWMAP);
    float* gates  = (float*)(ws + OFF_GATES);
    int*   counts = (int*)(ws + OFF_COUNTS);
    int*   picks  = (int*)(ws + OFF_PICKS);

    hipMemsetAsync(y, 0, (size_t)TT * DD * sizeof(float), stream);
    prep_kernel<<<4096 + 256, 256, 0, stream>>>(x, wg, w1, w2, xb, w1t, w2t, picks, gates);
    bucket_build<<<EE, 256, 0, stream>>>(picks, rowmap, counts);
    moe_gemm<1><<<dim3(HH / 128, CAP / 128, EE), 256, 0, stream>>>(
        xb, w1t, b1, rowmap, counts, gates, (void*)abuf);
    moe_gemm<2><<<dim3(DD / 128, CAP / 128, EE), 256, 0, stream>>>(
        abuf, w2t, b2, rowmap, counts, gates, (void*)y);
}

// Round 6
// 243.342 us; speedup vs baseline: 1.5239x; 1.1285x over previous
//
#include <hip/hip_runtime.h>
#include <hip/hip_bf16.h>
#include <math.h>

#define TT 4096
#define EE 8
#define DD 1024
#define HH 1024
#define CAP 4096

typedef __attribute__((ext_vector_type(8))) short bf16x8;
typedef __attribute__((ext_vector_type(4))) float f32x4;

// async global->LDS, 16B per lane; LDS dest is wave-uniform base + lane*16
#define GLL16(gp, lp)                                                                   \
    __builtin_amdgcn_global_load_lds((__attribute__((address_space(1))) void*)(gp),     \
                                     (__attribute__((address_space(3))) void*)(lp),     \
                                     16, 0, 0)

// ---------------- workspace layout (bytes) ----------------
static const size_t OFF_XB     = 0;                         // bf16 [4096][1024]  8 MB
static const size_t OFF_W1T    = 8u * 1024 * 1024;          // bf16 [8][H][D]    16 MB
static const size_t OFF_W2T    = 24u * 1024 * 1024;         // bf16 [8][D][H]    16 MB
static const size_t OFF_ABUF   = 40u * 1024 * 1024;         // bf16 [8192][1024] 16 MB
static const size_t OFF_OBUF   = 56u * 1024 * 1024;         // f32  [8192][1024] 32 MB
static const size_t OFF_ROWMAP = 88u * 1024 * 1024;         // int  [8][4096]   128 KB
static const size_t OFF_GATES  = OFF_ROWMAP + 8 * CAP * 4;  // f32  [8192]       32 KB
static const size_t OFF_COUNTS = OFF_GATES + 8192 * 4;      // int  [8]
static const size_t OFF_PICKS  = OFF_COUNTS + 256;          // int  [4096]       16 KB

// ---------------- prep: fused weight transpose (blocks 0..4095) + gating (4096..4351) ----
__global__ __launch_bounds__(256) void prep_kernel(
    const float* __restrict__ x, const float* __restrict__ wg,
    const float* __restrict__ w1, const float* __restrict__ w2,
    __hip_bfloat16* __restrict__ xb,
    __hip_bfloat16* __restrict__ w1t, __hip_bfloat16* __restrict__ w2t,
    int* __restrict__ picks, float* __restrict__ gates)
{
    __shared__ float tl[64][65];
    const int bid = blockIdx.x;
    const int tid = threadIdx.x;

    if (bid < 4096) {
        // ---- transpose path: 16 matrices x 256 tiles of 64x64 ----
        const int mat = bid >> 8;
        const int tt = bid & 255;
        const int R = (tt >> 4) * 64;   // src row base (k)
        const int C = (tt & 15) * 64;   // src col base (n)
        const float* src = (mat < EE ? w1 : w2) + (size_t)(mat & 7) * DD * HH;
        __hip_bfloat16* dst = (mat < EE ? w1t : w2t) + (size_t)(mat & 7) * DD * HH;

        const int lrow = tid >> 4;
        const int c4 = tid & 15;
#pragma unroll
        for (int i = 0; i < 4; ++i) {
            const int r = lrow + i * 16;
            float4 v = *(const float4*)(src + (size_t)(R + r) * 1024 + C + c4 * 4);
            tl[r][c4 * 4 + 0] = v.x;
            tl[r][c4 * 4 + 1] = v.y;
            tl[r][c4 * 4 + 2] = v.z;
            tl[r][c4 * 4 + 3] = v.w;
        }
        __syncthreads();
        const int seg = tid & 7;
        const int orow0 = tid >> 3;
#pragma unroll
        for (int p = 0; p < 2; ++p) {
            const int orow = orow0 + p * 32;
            unsigned short u[8];
#pragma unroll
            for (int j = 0; j < 8; ++j) {
                __hip_bfloat16 h = __float2bfloat16(tl[seg * 8 + j][orow]);
                u[j] = *(unsigned short*)&h;
            }
            *(ushort4*)(dst + (size_t)(C + orow) * 1024 + R + seg * 8)     = (ushort4){u[0], u[1], u[2], u[3]};
            *(ushort4*)(dst + (size_t)(C + orow) * 1024 + R + seg * 8 + 4) = (ushort4){u[4], u[5], u[6], u[7]};
        }
        return;
    }

    // ---- gate path ----
    const int lane = tid & 63;
    const int wave = tid >> 6;
    const int tbase = (bid - 4096) * 16 + wave * 4;

    for (int i = 0; i < 4; ++i) {
        const int t = tbase + i;
        const float4* xr = (const float4*)(x + (size_t)t * DD);
        ushort4* xbr = (ushort4*)(xb + (size_t)t * DD);

        float acc[EE];
#pragma unroll
        for (int e = 0; e < EE; ++e) acc[e] = 0.f;

#pragma unroll
        for (int c = 0; c < 4; ++c) {
            const int v4 = lane + 64 * c;
            float4 xv = xr[v4];
            __hip_bfloat16 h0 = __float2bfloat16(xv.x);
            __hip_bfloat16 h1 = __float2bfloat16(xv.y);
            __hip_bfloat16 h2 = __float2bfloat16(xv.z);
            __hip_bfloat16 h3 = __float2bfloat16(xv.w);
            ushort4 s;
            s.x = *(unsigned short*)&h0; s.y = *(unsigned short*)&h1;
            s.z = *(unsigned short*)&h2; s.w = *(unsigned short*)&h3;
            xbr[v4] = s;
            const float4* wrow = (const float4*)(wg + (size_t)(4 * v4) * EE);
            const float xs[4] = {xv.x, xv.y, xv.z, xv.w};
#pragma unroll
            for (int q = 0; q < 4; ++q) {
                float4 w0 = wrow[q * 2];
                float4 w1v = wrow[q * 2 + 1];
                acc[0] = fmaf(xs[q], w0.x, acc[0]);
                acc[1] = fmaf(xs[q], w0.y, acc[1]);
                acc[2] = fmaf(xs[q], w0.z, acc[2]);
                acc[3] = fmaf(xs[q], w0.w, acc[3]);
                acc[4] = fmaf(xs[q], w1v.x, acc[4]);
                acc[5] = fmaf(xs[q], w1v.y, acc[5]);
                acc[6] = fmaf(xs[q], w1v.z, acc[6]);
                acc[7] = fmaf(xs[q], w1v.w, acc[7]);
            }
        }
#pragma unroll
        for (int off = 32; off > 0; off >>= 1) {
#pragma unroll
            for (int e = 0; e < EE; ++e) acc[e] += __shfl_xor(acc[e], off, 64);
        }
        if (lane == 0) {
            float mx = acc[0];
#pragma unroll
            for (int e = 1; e < EE; ++e) mx = fmaxf(mx, acc[e]);
            float p[EE];
            float s = 0.f;
#pragma unroll
            for (int e = 0; e < EE; ++e) { p[e] = expf(acc[e] - mx); s += p[e]; }
            int i0 = 0;
#pragma unroll
            for (int e = 1; e < EE; ++e) if (acc[e] > acc[i0]) i0 = e;
            int i1 = (i0 == 0) ? 1 : 0;
#pragma unroll
            for (int e = 0; e < EE; ++e) {
                if (e != i0 && acc[e] > acc[i1]) i1 = e;
            }
            float v0 = p[i0] / s, v1 = p[i1] / s;
            float den = v0 + v1 + 1e-6f;
            gates[t * 2 + 0] = v0 / den;
            gates[t * 2 + 1] = v1 / den;
            picks[t] = i0 | (i1 << 4);
        }
    }
}

// ---------------- bucket build (deterministic, no global atomics) ----------------
__global__ __launch_bounds__(256) void bucket_build(
    const int* __restrict__ picks, int* __restrict__ rowmap, int* __restrict__ counts)
{
    const int e = blockIdx.x;
    const int tid = threadIdx.x;
    const int lane = tid & 63;
    const int wave = tid >> 6;
    __shared__ int wsum[4];

    int runtot = 0;
    for (int tb = 0; tb < TT; tb += 256) {
        const int t = tb + tid;
        const int p = picks[t];
        const int m0 = ((p & 15) == e) ? 1 : 0;
        const int m1 = (((p >> 4) & 15) == e) ? 1 : 0;
        const int c = m0 + m1;
        int incl = c;
#pragma unroll
        for (int off = 1; off < 64; off <<= 1) {
            int v = __shfl_up(incl, off, 64);
            if (lane >= off) incl += v;
        }
        if (lane == 63) wsum[wave] = incl;
        __syncthreads();
        int wbase = 0;
#pragma unroll
        for (int w = 0; w < 4; ++w) wbase += (w < wave) ? wsum[w] : 0;
        int slot = runtot + wbase + incl - c;
        if (m0) { rowmap[e * CAP + slot] = t * 2; slot += 1; }
        if (m1) { rowmap[e * CAP + slot] = t * 2 + 1; }
        runtot += wsum[0] + wsum[1] + wsum[2] + wsum[3];
        __syncthreads();
    }
    if (tid == 0) counts[e] = runtot;
}

// ---------------- grouped GEMM: 128m x 64n tile, BK=64, single-buffer, 2-barrier -------
// vs round-2 (128x128, BK=32, 2 blocks/CU, 44.5us): half n-tile doubles the grid to
// ~1024 live blocks = 4 blocks/CU (TLP hides the drain), BK=64 halves barrier count.
// LDS 24KB -> 6 blocks/CU possible, no occupancy cliff. B-tile reuse (8 m-blocks)
// unchanged; A logical traffic x2 but L3-resident.
// LAYER==1: out = gelu(C + b1) -> bf16 abuf[(t,k) slot]
// LAYER==2: out = (C + b2) * gate -> f32 obuf[(t,k) slot]
template <int LAYER>
__global__ __launch_bounds__(256) void moe_gemm(
    const __hip_bfloat16* __restrict__ Abase,
    const __hip_bfloat16* __restrict__ Bbase,   // [E][N=1024][K=1024], K contiguous
    const float* __restrict__ bias,             // [E][1024]
    const int* __restrict__ rowmap,
    const int* __restrict__ counts,
    const float* __restrict__ gates,
    void* __restrict__ OutP)
{
    const int e = blockIdx.z;
    const int cnt = counts[e];
    const int m0 = blockIdx.y * 128;
    if (m0 >= cnt) return;
    const int n0 = blockIdx.x * 64;
    const int tid = threadIdx.x;
    const int lane = tid & 63;
    const int wave = tid >> 6;
    const int wm = (wave >> 1) * 64;   // wave's 64m x 32n quadrant
    const int wn = (wave & 1) * 32;
    const int lrow = lane & 15;
    const int quad = lane >> 4;

    __shared__ __hip_bfloat16 As[128 * 64];   // [m][k] k-contig, 128B rows, 16 KB
    __shared__ __hip_bfloat16 Bs[64 * 64];    // [n][k] k-contig, 128B rows,  8 KB

    // staging sources. A: 4 issues/thread, issue j covers LDS rows 32*wave+8j..+7,
    // lane l -> row +(l>>3), 16B chunk (l&7). B: 2 issues, rows 16*wave+8j..+7.
    const __hip_bfloat16* Bexp = Bbase + (size_t)e * DD * HH;
    const __hip_bfloat16* gA[4];
    const __hip_bfloat16* gB[2];
#pragma unroll
    for (int j = 0; j < 4; ++j) {
        const int gm = m0 + 32 * wave + 8 * j + (lane >> 3);
        const int ent = rowmap[e * CAP + (gm < cnt ? gm : 0)];
        const size_t src = (size_t)(LAYER == 1 ? (ent >> 1) : ent);
        gA[j] = Abase + src * DD + (lane & 7) * 8;
    }
#pragma unroll
    for (int j = 0; j < 2; ++j) {
        const int gn = n0 + 16 * wave + 8 * j + (lane >> 3);
        gB[j] = Bexp + (size_t)gn * DD + (lane & 7) * 8;
    }
    char* ldsA = (char*)As + wave * 4096;   // + j*1024 + lane*16
    char* ldsB = (char*)Bs + wave * 2048;   // + j*1024 + lane*16

    f32x4 acc[4][2];
#pragma unroll
    for (int i = 0; i < 4; ++i)
#pragma unroll
        for (int j = 0; j < 2; ++j) acc[i][j] = (f32x4){0.f, 0.f, 0.f, 0.f};

    const bf16x8* Av = (const bf16x8*)As;   // index: row*8 + quad + 4*s
    const bf16x8* Bv = (const bf16x8*)Bs;

    for (int kt = 0; kt < DD / 64; ++kt) {
        const int ko = kt * 64;
#pragma unroll
        for (int j = 0; j < 4; ++j) GLL16(gA[j] + ko, ldsA + j * 1024);
#pragma unroll
        for (int j = 0; j < 2; ++j) GLL16(gB[j] + ko, ldsB + j * 1024);
        __syncthreads();

#pragma unroll
        for (int s = 0; s < 2; ++s) {
            bf16x8 af[4], bfr[2];
#pragma unroll
            for (int i = 0; i < 4; ++i)
                af[i] = Av[(wm + i * 16 + lrow) * 8 + quad + 4 * s];
#pragma unroll
            for (int i = 0; i < 2; ++i)
                bfr[i] = Bv[(wn + i * 16 + lrow) * 8 + quad + 4 * s];
#pragma unroll
            for (int mi = 0; mi < 4; ++mi)
#pragma unroll
                for (int ni = 0; ni < 2; ++ni)
                    acc[mi][ni] = __builtin_amdgcn_mfma_f32_16x16x32_bf16(
                        af[mi], bfr[ni], acc[mi][ni], 0, 0, 0);
        }
        __syncthreads();
    }

    // epilogue: C/D layout col = lane&15, row = quad*4 + reg (m89/m91 verified)
    if (LAYER == 1) {
        __hip_bfloat16* abuf = (__hip_bfloat16*)OutP;
#pragma unroll
        for (int mi = 0; mi < 4; ++mi) {
#pragma unroll
            for (int r = 0; r < 4; ++r) {
                const int mrow = wm + mi * 16 + quad * 4 + r;
                const int gm = m0 + mrow;
                if (gm < cnt) {
                    const int ent = rowmap[e * CAP + gm];
                    __hip_bfloat16* orow = abuf + (size_t)ent * HH + n0 + wn + lrow;
#pragma unroll
                    for (int ni = 0; ni < 2; ++ni) {
                        float v = acc[mi][ni][r] + bias[e * HH + n0 + wn + ni * 16 + lrow];
                        v = 0.5f * v * (1.f + erff(v * 0.70710678118654752f));  // exact GELU
                        orow[ni * 16] = __float2bfloat16(v);
                    }
                }
            }
        }
    } else {
        float* obuf = (float*)OutP;
#pragma unroll
        for (int mi = 0; mi < 4; ++mi) {
#pragma unroll
            for (int r = 0; r < 4; ++r) {
                const int mrow = wm + mi * 16 + quad * 4 + r;
                const int gm = m0 + mrow;
                if (gm < cnt) {
                    const int ent = rowmap[e * CAP + gm];
                    const float g = gates[ent];
                    float* orow = obuf + (size_t)ent * DD + n0 + wn + lrow;
#pragma unroll
                    for (int ni = 0; ni < 2; ++ni) {
                        float v = acc[mi][ni][r] + bias[e * DD + n0 + wn + ni * 16 + lrow];
                        orow[ni * 16] = v * g;
                    }
                }
            }
        }
    }
}

// ---------------- combine: y[t] = o[t,0] + o[t,1] ----------------
__global__ __launch_bounds__(256) void combine_kernel(
    const float* __restrict__ obuf, float* __restrict__ y)
{
    const size_t i = (size_t)blockIdx.x * 256 + threadIdx.x;
    const size_t t = i >> 8;
    const size_t c = i & 255;
    const float4* o0 = (const float4*)(obuf + t * 2 * DD);
    float4 a = o0[c];
    float4 b = o0[256 + c];
    float4 r;
    r.x = a.x + b.x; r.y = a.y + b.y; r.z = a.z + b.z; r.w = a.w + b.w;
    ((float4*)y)[i] = r;
}

extern "C" void kernel_launch(void* const* d_in, const int* in_sizes, int n_in,
                              void* d_out, int out_size, void* d_ws, size_t ws_size,
                              hipStream_t stream)
{
    const float* x  = (const float*)d_in[0];
    const float* w1 = (const float*)d_in[1];
    const float* b1 = (const float*)d_in[2];
    const float* w2 = (const float*)d_in[3];
    const float* b2 = (const float*)d_in[4];
    const float* wg = (const float*)d_in[5];
    float* y = (float*)d_out;

    char* ws = (char*)d_ws;
    __hip_bfloat16* xb   = (__hip_bfloat16*)(ws + OFF_XB);
    __hip_bfloat16* w1t  = (__hip_bfloat16*)(ws + OFF_W1T);
    __hip_bfloat16* w2t  = (__hip_bfloat16*)(ws + OFF_W2T);
    __hip_bfloat16* abuf = (__hip_bfloat16*)(ws + OFF_ABUF);
    float* obuf  = (float*)(ws + OFF_OBUF);
    int*   rowmap = (int*)(ws + OFF_ROWMAP);
    float* gates  = (float*)(ws + OFF_GATES);
    int*   counts = (int*)(ws + OFF_COUNTS);
    int*   picks  = (int*)(ws + OFF_PICKS);

    prep_kernel<<<4096 + 256, 256, 0, stream>>>(x, wg, w1, w2, xb, w1t, w2t, picks, gates);
    bucket_build<<<EE, 256, 0, stream>>>(picks, rowmap, counts);
    moe_gemm<1><<<dim3(HH / 64, CAP / 128, EE), 256, 0, stream>>>(
        xb, w1t, b1, rowmap, counts, gates, (void*)abuf);
    moe_gemm<2><<<dim3(DD / 64, CAP / 128, EE), 256, 0, stream>>>(
        abuf, w2t, b2, rowmap, counts, gates, (void*)obuf);
    combine_kernel<<<TT * DD / 4 / 256, 256, 0, stream>>>(obuf, y);
}

// Round 7
// 238.001 us; speedup vs baseline: 1.5581x; 1.0224x over previous
//
#include <hip/hip_runtime.h>
#include <hip/hip_bf16.h>
#include <math.h>

#define TT 4096
#define EE 8
#define DD 1024
#define HH 1024
#define CAP 4096

typedef __attribute__((ext_vector_type(8))) short bf16x8;
typedef __attribute__((ext_vector_type(4))) float f32x4;

// async global->LDS, 16B per lane; LDS dest is wave-uniform base + lane*16
#define GLL16(gp, lp)                                                                   \
    __builtin_amdgcn_global_load_lds((__attribute__((address_space(1))) void*)(gp),     \
                                     (__attribute__((address_space(3))) void*)(lp),     \
                                     16, 0, 0)

// ---------------- workspace layout (bytes) ----------------
static const size_t OFF_XB     = 0;                         // bf16 [4096][1024]  8 MB
static const size_t OFF_W1T    = 8u * 1024 * 1024;          // bf16 [8][H][D]    16 MB
static const size_t OFF_W2T    = 24u * 1024 * 1024;         // bf16 [8][D][H]    16 MB
static const size_t OFF_ABUF   = 40u * 1024 * 1024;         // bf16 [8192][1024] 16 MB
static const size_t OFF_OBUF   = 56u * 1024 * 1024;         // f32  [8192][1024] 32 MB
static const size_t OFF_ROWMAP = 88u * 1024 * 1024;         // int  [8][4096]   128 KB
static const size_t OFF_GATES  = OFF_ROWMAP + 8 * CAP * 4;  // f32  [8192]       32 KB
static const size_t OFF_COUNTS = OFF_GATES + 8192 * 4;      // int  [8]
static const size_t OFF_PICKS  = OFF_COUNTS + 256;          // int  [4096]       16 KB

#define NGATE 1024   // gate blocks come FIRST (long-pole work spread 4x wider than r6)

// ---------------- prep: gating (blocks 0..1023, 1 token/wave) + transpose (1024..5119) --
__global__ __launch_bounds__(256) void prep_kernel(
    const float* __restrict__ x, const float* __restrict__ wg,
    const float* __restrict__ w1, const float* __restrict__ w2,
    __hip_bfloat16* __restrict__ xb,
    __hip_bfloat16* __restrict__ w1t, __hip_bfloat16* __restrict__ w2t,
    int* __restrict__ picks, float* __restrict__ gates)
{
    __shared__ float tl[64][65];
    const int bid = blockIdx.x;
    const int tid = threadIdx.x;

    if (bid >= NGATE) {
        // ---- transpose path: 16 matrices x 256 tiles of 64x64 ----
        const int bt = bid - NGATE;
        const int mat = bt >> 8;
        const int tt = bt & 255;
        const int R = (tt >> 4) * 64;   // src row base (k)
        const int C = (tt & 15) * 64;   // src col base (n)
        const float* src = (mat < EE ? w1 : w2) + (size_t)(mat & 7) * DD * HH;
        __hip_bfloat16* dst = (mat < EE ? w1t : w2t) + (size_t)(mat & 7) * DD * HH;

        const int lrow = tid >> 4;
        const int c4 = tid & 15;
#pragma unroll
        for (int i = 0; i < 4; ++i) {
            const int r = lrow + i * 16;
            float4 v = *(const float4*)(src + (size_t)(R + r) * 1024 + C + c4 * 4);
            tl[r][c4 * 4 + 0] = v.x;
            tl[r][c4 * 4 + 1] = v.y;
            tl[r][c4 * 4 + 2] = v.z;
            tl[r][c4 * 4 + 3] = v.w;
        }
        __syncthreads();
        const int seg = tid & 7;
        const int orow0 = tid >> 3;
#pragma unroll
        for (int p = 0; p < 2; ++p) {
            const int orow = orow0 + p * 32;
            unsigned short u[8];
#pragma unroll
            for (int j = 0; j < 8; ++j) {
                __hip_bfloat16 h = __float2bfloat16(tl[seg * 8 + j][orow]);
                u[j] = *(unsigned short*)&h;
            }
            *(ushort4*)(dst + (size_t)(C + orow) * 1024 + R + seg * 8)     = (ushort4){u[0], u[1], u[2], u[3]};
            *(ushort4*)(dst + (size_t)(C + orow) * 1024 + R + seg * 8 + 4) = (ushort4){u[4], u[5], u[6], u[7]};
        }
        return;
    }

    // ---- gate path: one token per wave ----
    const int lane = tid & 63;
    const int wave = tid >> 6;
    const int t = bid * 4 + wave;
    {
        const float4* xr = (const float4*)(x + (size_t)t * DD);
        ushort4* xbr = (ushort4*)(xb + (size_t)t * DD);

        float acc[EE];
#pragma unroll
        for (int e = 0; e < EE; ++e) acc[e] = 0.f;

#pragma unroll
        for (int c = 0; c < 4; ++c) {
            const int v4 = lane + 64 * c;
            float4 xv = xr[v4];
            __hip_bfloat16 h0 = __float2bfloat16(xv.x);
            __hip_bfloat16 h1 = __float2bfloat16(xv.y);
            __hip_bfloat16 h2 = __float2bfloat16(xv.z);
            __hip_bfloat16 h3 = __float2bfloat16(xv.w);
            ushort4 s;
            s.x = *(unsigned short*)&h0; s.y = *(unsigned short*)&h1;
            s.z = *(unsigned short*)&h2; s.w = *(unsigned short*)&h3;
            xbr[v4] = s;
            const float4* wrow = (const float4*)(wg + (size_t)(4 * v4) * EE);
            const float xs[4] = {xv.x, xv.y, xv.z, xv.w};
#pragma unroll
            for (int q = 0; q < 4; ++q) {
                float4 w0 = wrow[q * 2];
                float4 w1v = wrow[q * 2 + 1];
                acc[0] = fmaf(xs[q], w0.x, acc[0]);
                acc[1] = fmaf(xs[q], w0.y, acc[1]);
                acc[2] = fmaf(xs[q], w0.z, acc[2]);
                acc[3] = fmaf(xs[q], w0.w, acc[3]);
                acc[4] = fmaf(xs[q], w1v.x, acc[4]);
                acc[5] = fmaf(xs[q], w1v.y, acc[5]);
                acc[6] = fmaf(xs[q], w1v.z, acc[6]);
                acc[7] = fmaf(xs[q], w1v.w, acc[7]);
            }
        }
#pragma unroll
        for (int off = 32; off > 0; off >>= 1) {
#pragma unroll
            for (int e = 0; e < EE; ++e) acc[e] += __shfl_xor(acc[e], off, 64);
        }
        if (lane == 0) {
            float mx = acc[0];
#pragma unroll
            for (int e = 1; e < EE; ++e) mx = fmaxf(mx, acc[e]);
            float p[EE];
            float s = 0.f;
#pragma unroll
            for (int e = 0; e < EE; ++e) { p[e] = expf(acc[e] - mx); s += p[e]; }
            int i0 = 0;
#pragma unroll
            for (int e = 1; e < EE; ++e) if (acc[e] > acc[i0]) i0 = e;
            int i1 = (i0 == 0) ? 1 : 0;
#pragma unroll
            for (int e = 0; e < EE; ++e) {
                if (e != i0 && acc[e] > acc[i1]) i1 = e;
            }
            float v0 = p[i0] / s, v1 = p[i1] / s;
            float den = v0 + v1 + 1e-6f;
            gates[t * 2 + 0] = v0 / den;
            gates[t * 2 + 1] = v1 / den;
            picks[t] = i0 | (i1 << 4);
        }
    }
}

// ---------------- bucket build (deterministic, no global atomics) ----------------
__global__ __launch_bounds__(256) void bucket_build(
    const int* __restrict__ picks, int* __restrict__ rowmap, int* __restrict__ counts)
{
    const int e = blockIdx.x;
    const int tid = threadIdx.x;
    const int lane = tid & 63;
    const int wave = tid >> 6;
    __shared__ int wsum[4];

    int runtot = 0;
    for (int tb = 0; tb < TT; tb += 256) {
        const int t = tb + tid;
        const int p = picks[t];
        const int m0 = ((p & 15) == e) ? 1 : 0;
        const int m1 = (((p >> 4) & 15) == e) ? 1 : 0;
        const int c = m0 + m1;
        int incl = c;
#pragma unroll
        for (int off = 1; off < 64; off <<= 1) {
            int v = __shfl_up(incl, off, 64);
            if (lane >= off) incl += v;
        }
        if (lane == 63) wsum[wave] = incl;
        __syncthreads();
        int wbase = 0;
#pragma unroll
        for (int w = 0; w < 4; ++w) wbase += (w < wave) ? wsum[w] : 0;
        int slot = runtot + wbase + incl - c;
        if (m0) { rowmap[e * CAP + slot] = t * 2; slot += 1; }
        if (m1) { rowmap[e * CAP + slot] = t * 2 + 1; }
        runtot += wsum[0] + wsum[1] + wsum[2] + wsum[3];
        __syncthreads();
    }
    if (tid == 0) counts[e] = runtot;
}

// ---------------- grouped GEMM: 128m x 64n tile, BK=64 via 2x 32-k sub-buffers ----------
// n=64 keeps grid at ~1024 live blocks = 4 blocks/CU (TLP, round 6 win); sub-buffers
// restore the round-2 [row][32k] 64B-row LDS layout whose conflicts are free
// (round 6's monolithic 128B rows aliased banks: 10M conflict cycles = 34% of time).
// 16 barriers, 6 outstanding GLL16/thread per drain, LDS 24 KB.
// LAYER==1: out = gelu(C + b1) -> bf16 abuf[(t,k) slot]
// LAYER==2: out = (C + b2) * gate -> f32 obuf[(t,k) slot]
template <int LAYER>
__global__ __launch_bounds__(256) void moe_gemm(
    const __hip_bfloat16* __restrict__ Abase,
    const __hip_bfloat16* __restrict__ Bbase,   // [E][N=1024][K=1024], K contiguous
    const float* __restrict__ bias,             // [E][1024]
    const int* __restrict__ rowmap,
    const int* __restrict__ counts,
    const float* __restrict__ gates,
    void* __restrict__ OutP)
{
    const int e = blockIdx.z;
    const int cnt = counts[e];
    const int m0 = blockIdx.y * 128;
    if (m0 >= cnt) return;
    const int n0 = blockIdx.x * 64;
    const int tid = threadIdx.x;
    const int lane = tid & 63;
    const int wave = tid >> 6;
    const int wm = (wave >> 1) * 64;   // wave's 64m x 32n quadrant
    const int wn = (wave & 1) * 32;
    const int lrow = lane & 15;
    const int quad = lane >> 4;

    __shared__ __hip_bfloat16 As[2][128 * 32];   // 16 KB  (64B rows: conflict-free)
    __shared__ __hip_bfloat16 Bs[2][64 * 32];    //  8 KB

    // staging sources (round-2 map): A rows tid>>2 and tid>>2+64, chunk (tid&3)*8
    const int ar0 = m0 + (tid >> 2);
    const int ar1 = ar0 + 64;
    const int e0 = rowmap[e * CAP + (ar0 < cnt ? ar0 : 0)];
    const int e1 = rowmap[e * CAP + (ar1 < cnt ? ar1 : 0)];
    const size_t src0 = (size_t)(LAYER == 1 ? (e0 >> 1) : e0);
    const size_t src1 = (size_t)(LAYER == 1 ? (e1 >> 1) : e1);
    const __hip_bfloat16* gA0 = Abase + src0 * DD + (tid & 3) * 8;
    const __hip_bfloat16* gA1 = Abase + src1 * DD + (tid & 3) * 8;
    const __hip_bfloat16* Bexp = Bbase + (size_t)e * DD * HH;
    const __hip_bfloat16* gB0 = Bexp + (size_t)(n0 + (tid >> 2)) * DD + (tid & 3) * 8;

    f32x4 acc[4][2];
#pragma unroll
    for (int i = 0; i < 4; ++i)
#pragma unroll
        for (int j = 0; j < 2; ++j) acc[i][j] = (f32x4){0.f, 0.f, 0.f, 0.f};

    for (int kt = 0; kt < DD / 64; ++kt) {
#pragma unroll
        for (int s = 0; s < 2; ++s) {
            const int ko = kt * 64 + s * 32;
            char* lA = (char*)&As[s][0] + wave * 1024;
            char* lB = (char*)&Bs[s][0] + wave * 1024;
            GLL16(gA0 + ko, lA);
            GLL16(gA1 + ko, lA + 4096);
            GLL16(gB0 + ko, lB);
        }
        __syncthreads();

#pragma unroll
        for (int s = 0; s < 2; ++s) {
            const bf16x8* Av = (const bf16x8*)&As[s][0];
            const bf16x8* Bv = (const bf16x8*)&Bs[s][0];
            bf16x8 af[4], bfr[2];
#pragma unroll
            for (int i = 0; i < 4; ++i)
                af[i] = Av[(wm + i * 16 + lrow) * 4 + quad];
#pragma unroll
            for (int i = 0; i < 2; ++i)
                bfr[i] = Bv[(wn + i * 16 + lrow) * 4 + quad];
#pragma unroll
            for (int mi = 0; mi < 4; ++mi)
#pragma unroll
                for (int ni = 0; ni < 2; ++ni)
                    acc[mi][ni] = __builtin_amdgcn_mfma_f32_16x16x32_bf16(
                        af[mi], bfr[ni], acc[mi][ni], 0, 0, 0);
        }
        __syncthreads();
    }

    // epilogue: C/D layout col = lane&15, row = quad*4 + reg (m89/m91 verified)
    if (LAYER == 1) {
        __hip_bfloat16* abuf = (__hip_bfloat16*)OutP;
#pragma unroll
        for (int mi = 0; mi < 4; ++mi) {
#pragma unroll
            for (int r = 0; r < 4; ++r) {
                const int mrow = wm + mi * 16 + quad * 4 + r;
                const int gm = m0 + mrow;
                if (gm < cnt) {
                    const int ent = rowmap[e * CAP + gm];
                    __hip_bfloat16* orow = abuf + (size_t)ent * HH + n0 + wn + lrow;
#pragma unroll
                    for (int ni = 0; ni < 2; ++ni) {
                        float v = acc[mi][ni][r] + bias[e * HH + n0 + wn + ni * 16 + lrow];
                        v = 0.5f * v * (1.f + erff(v * 0.70710678118654752f));  // exact GELU
                        orow[ni * 16] = __float2bfloat16(v);
                    }
                }
            }
        }
    } else {
        float* obuf = (float*)OutP;
#pragma unroll
        for (int mi = 0; mi < 4; ++mi) {
#pragma unroll
            for (int r = 0; r < 4; ++r) {
                const int mrow = wm + mi * 16 + quad * 4 + r;
                const int gm = m0 + mrow;
                if (gm < cnt) {
                    const int ent = rowmap[e * CAP + gm];
                    const float g = gates[ent];
                    float* orow = obuf + (size_t)ent * DD + n0 + wn + lrow;
#pragma unroll
                    for (int ni = 0; ni < 2; ++ni) {
                        float v = acc[mi][ni][r] + bias[e * DD + n0 + wn + ni * 16 + lrow];
                        orow[ni * 16] = v * g;
                    }
                }
            }
        }
    }
}

// ---------------- combine: y[t] = o[t,0] + o[t,1] ----------------
__global__ __launch_bounds__(256) void combine_kernel(
    const float* __restrict__ obuf, float* __restrict__ y)
{
    const size_t i = (size_t)blockIdx.x * 256 + threadIdx.x;
    const size_t t = i >> 8;
    const size_t c = i & 255;
    const float4* o0 = (const float4*)(obuf + t * 2 * DD);
    float4 a = o0[c];
    float4 b = o0[256 + c];
    float4 r;
    r.x = a.x + b.x; r.y = a.y + b.y; r.z = a.z + b.z; r.w = a.w + b.w;
    ((float4*)y)[i] = r;
}

extern "C" void kernel_launch(void* const* d_in, const int* in_sizes, int n_in,
                              void* d_out, int out_size, void* d_ws, size_t ws_size,
                              hipStream_t stream)
{
    const float* x  = (const float*)d_in[0];
    const float* w1 = (const float*)d_in[1];
    const float* b1 = (const float*)d_in[2];
    const float* w2 = (const float*)d_in[3];
    const float* b2 = (const float*)d_in[4];
    const float* wg = (const float*)d_in[5];
    float* y = (float*)d_out;

    char* ws = (char*)d_ws;
    __hip_bfloat16* xb   = (__hip_bfloat16*)(ws + OFF_XB);
    __hip_bfloat16* w1t  = (__hip_bfloat16*)(ws + OFF_W1T);
    __hip_bfloat16* w2t  = (__hip_bfloat16*)(ws + OFF_W2T);
    __hip_bfloat16* abuf = (__hip_bfloat16*)(ws + OFF_ABUF);
    float* obuf  = (float*)(ws + OFF_OBUF);
    int*   rowmap = (int*)(ws + OFF_ROWMAP);
    float* gates  = (float*)(ws + OFF_GATES);
    int*   counts = (int*)(ws + OFF_COUNTS);
    int*   picks  = (int*)(ws + OFF_PICKS);

    prep_kernel<<<NGATE + 4096, 256, 0, stream>>>(x, wg, w1, w2, xb, w1t, w2t, picks, gates);
    bucket_build<<<EE, 256, 0, stream>>>(picks, rowmap, counts);
    moe_gemm<1><<<dim3(HH / 64, CAP / 128, EE), 256, 0, stream>>>(
        xb, w1t, b1, rowmap, counts, gates, (void*)abuf);
    moe_gemm<2><<<dim3(DD / 64, CAP / 128, EE), 256, 0, stream>>>(
        abuf, w2t, b2, rowmap, counts, gates, (void*)obuf);
    combine_kernel<<<TT * DD / 4 / 256, 256, 0, stream>>>(obuf, y);
}

// Round 8
// 229.474 us; speedup vs baseline: 1.6160x; 1.0372x over previous
//
#include <hip/hip_runtime.h>
#include <hip/hip_bf16.h>
#include <math.h>

#define TT 4096
#define EE 8
#define DD 1024
#define HH 1024
#define CAP 4096

typedef __attribute__((ext_vector_type(8))) short bf16x8;
typedef __attribute__((ext_vector_type(4))) float f32x4;

// async global->LDS, 16B per lane; LDS dest is wave-uniform base + lane*16
#define GLL16(gp, lp)                                                                   \
    __builtin_amdgcn_global_load_lds((__attribute__((address_space(1))) void*)(gp),     \
                                     (__attribute__((address_space(3))) void*)(lp),     \
                                     16, 0, 0)

// ---------------- workspace layout (bytes) ----------------
static const size_t OFF_XB     = 0;                         // bf16 [4096][1024]  8 MB
static const size_t OFF_W1T    = 8u * 1024 * 1024;          // bf16 [8][H][D]    16 MB
static const size_t OFF_W2T    = 24u * 1024 * 1024;         // bf16 [8][D][H]    16 MB
static const size_t OFF_ABUF   = 40u * 1024 * 1024;         // bf16 [8192][1024] 16 MB
static const size_t OFF_OBUF   = 56u * 1024 * 1024;         // f32  [8192][1024] 32 MB
static const size_t OFF_ROWMAP = 88u * 1024 * 1024;         // int  [8][4096]   128 KB
static const size_t OFF_GATES  = OFF_ROWMAP + 8 * CAP * 4;  // f32  [8192]       32 KB
static const size_t OFF_COUNTS = OFF_GATES + 8192 * 4;      // int  [8]
static const size_t OFF_PICKS  = OFF_COUNTS + 256;          // int  [4096]       16 KB

#define NGATE 1024   // gate blocks come FIRST

// ---------------- prep: gating (blocks 0..1023, 1 token/wave) + transpose (1024..5119) --
__global__ __launch_bounds__(256) void prep_kernel(
    const float* __restrict__ x, const float* __restrict__ wg,
    const float* __restrict__ w1, const float* __restrict__ w2,
    __hip_bfloat16* __restrict__ xb,
    __hip_bfloat16* __restrict__ w1t, __hip_bfloat16* __restrict__ w2t,
    int* __restrict__ picks, float* __restrict__ gates)
{
    __shared__ float tl[64][65];
    const int bid = blockIdx.x;
    const int tid = threadIdx.x;

    if (bid >= NGATE) {
        // ---- transpose path: 16 matrices x 256 tiles of 64x64 ----
        const int bt = bid - NGATE;
        const int mat = bt >> 8;
        const int tt = bt & 255;
        const int R = (tt >> 4) * 64;   // src row base (k)
        const int C = (tt & 15) * 64;   // src col base (n)
        const float* src = (mat < EE ? w1 : w2) + (size_t)(mat & 7) * DD * HH;
        __hip_bfloat16* dst = (mat < EE ? w1t : w2t) + (size_t)(mat & 7) * DD * HH;

        const int lrow = tid >> 4;
        const int c4 = tid & 15;
#pragma unroll
        for (int i = 0; i < 4; ++i) {
            const int r = lrow + i * 16;
            float4 v = *(const float4*)(src + (size_t)(R + r) * 1024 + C + c4 * 4);
            tl[r][c4 * 4 + 0] = v.x;
            tl[r][c4 * 4 + 1] = v.y;
            tl[r][c4 * 4 + 2] = v.z;
            tl[r][c4 * 4 + 3] = v.w;
        }
        __syncthreads();
        const int seg = tid & 7;
        const int orow0 = tid >> 3;
#pragma unroll
        for (int p = 0; p < 2; ++p) {
            const int orow = orow0 + p * 32;
            unsigned short u[8];
#pragma unroll
            for (int j = 0; j < 8; ++j) {
                __hip_bfloat16 h = __float2bfloat16(tl[seg * 8 + j][orow]);
                u[j] = *(unsigned short*)&h;
            }
            *(ushort4*)(dst + (size_t)(C + orow) * 1024 + R + seg * 8)     = (ushort4){u[0], u[1], u[2], u[3]};
            *(ushort4*)(dst + (size_t)(C + orow) * 1024 + R + seg * 8 + 4) = (ushort4){u[4], u[5], u[6], u[7]};
        }
        return;
    }

    // ---- gate path: one token per wave ----
    const int lane = tid & 63;
    const int wave = tid >> 6;
    const int t = bid * 4 + wave;
    {
        const float4* xr = (const float4*)(x + (size_t)t * DD);
        ushort4* xbr = (ushort4*)(xb + (size_t)t * DD);

        float acc[EE];
#pragma unroll
        for (int e = 0; e < EE; ++e) acc[e] = 0.f;

#pragma unroll
        for (int c = 0; c < 4; ++c) {
            const int v4 = lane + 64 * c;
            float4 xv = xr[v4];
            __hip_bfloat16 h0 = __float2bfloat16(xv.x);
            __hip_bfloat16 h1 = __float2bfloat16(xv.y);
            __hip_bfloat16 h2 = __float2bfloat16(xv.z);
            __hip_bfloat16 h3 = __float2bfloat16(xv.w);
            ushort4 s;
            s.x = *(unsigned short*)&h0; s.y = *(unsigned short*)&h1;
            s.z = *(unsigned short*)&h2; s.w = *(unsigned short*)&h3;
            xbr[v4] = s;
            const float4* wrow = (const float4*)(wg + (size_t)(4 * v4) * EE);
            const float xs[4] = {xv.x, xv.y, xv.z, xv.w};
#pragma unroll
            for (int q = 0; q < 4; ++q) {
                float4 w0 = wrow[q * 2];
                float4 w1v = wrow[q * 2 + 1];
                acc[0] = fmaf(xs[q], w0.x, acc[0]);
                acc[1] = fmaf(xs[q], w0.y, acc[1]);
                acc[2] = fmaf(xs[q], w0.z, acc[2]);
                acc[3] = fmaf(xs[q], w0.w, acc[3]);
                acc[4] = fmaf(xs[q], w1v.x, acc[4]);
                acc[5] = fmaf(xs[q], w1v.y, acc[5]);
                acc[6] = fmaf(xs[q], w1v.z, acc[6]);
                acc[7] = fmaf(xs[q], w1v.w, acc[7]);
            }
        }
#pragma unroll
        for (int off = 32; off > 0; off >>= 1) {
#pragma unroll
            for (int e = 0; e < EE; ++e) acc[e] += __shfl_xor(acc[e], off, 64);
        }
        if (lane == 0) {
            float mx = acc[0];
#pragma unroll
            for (int e = 1; e < EE; ++e) mx = fmaxf(mx, acc[e]);
            float p[EE];
            float s = 0.f;
#pragma unroll
            for (int e = 0; e < EE; ++e) { p[e] = expf(acc[e] - mx); s += p[e]; }
            int i0 = 0;
#pragma unroll
            for (int e = 1; e < EE; ++e) if (acc[e] > acc[i0]) i0 = e;
            int i1 = (i0 == 0) ? 1 : 0;
#pragma unroll
            for (int e = 0; e < EE; ++e) {
                if (e != i0 && acc[e] > acc[i1]) i1 = e;
            }
            float v0 = p[i0] / s, v1 = p[i1] / s;
            float den = v0 + v1 + 1e-6f;
            gates[t * 2 + 0] = v0 / den;
            gates[t * 2 + 1] = v1 / den;
            picks[t] = i0 | (i1 << 4);
        }
    }
}

// ---------------- bucket build (deterministic, no global atomics) ----------------
__global__ __launch_bounds__(256) void bucket_build(
    const int* __restrict__ picks, int* __restrict__ rowmap, int* __restrict__ counts)
{
    const int e = blockIdx.x;
    const int tid = threadIdx.x;
    const int lane = tid & 63;
    const int wave = tid >> 6;
    __shared__ int wsum[4];

    int runtot = 0;
    for (int tb = 0; tb < TT; tb += 256) {
        const int t = tb + tid;
        const int p = picks[t];
        const int m0 = ((p & 15) == e) ? 1 : 0;
        const int m1 = (((p >> 4) & 15) == e) ? 1 : 0;
        const int c = m0 + m1;
        int incl = c;
#pragma unroll
        for (int off = 1; off < 64; off <<= 1) {
            int v = __shfl_up(incl, off, 64);
            if (lane >= off) incl += v;
        }
        if (lane == 63) wsum[wave] = incl;
        __syncthreads();
        int wbase = 0;
#pragma unroll
        for (int w = 0; w < 4; ++w) wbase += (w < wave) ? wsum[w] : 0;
        int slot = runtot + wbase + incl - c;
        if (m0) { rowmap[e * CAP + slot] = t * 2; slot += 1; }
        if (m1) { rowmap[e * CAP + slot] = t * 2 + 1; }
        runtot += wsum[0] + wsum[1] + wsum[2] + wsum[3];
        __syncthreads();
    }
    if (tid == 0) counts[e] = runtot;
}

// ---------------- grouped GEMM: 128x128 tile, 512 threads (8 waves), BK=64 -------------
// Traffic-optimal 128x128 tile (r2: 41.5 MB FETCH) + 2x TLP: 512-thread blocks give
// 16 waves/CU at the same 2 blocks/CU (r2 had 8). Each wave owns a 64m x 32n quadrant.
// BK=64 via 2x [128][32] sub-buffers (64B rows: free 2-way conflicts), 16 barriers.
// LDS 32 KB; ~80 VGPR -> no occupancy cliff.
// LAYER==1: out = gelu(C + b1) -> bf16 abuf[(t,k) slot]
// LAYER==2: out = (C + b2) * gate -> f32 obuf[(t,k) slot]
template <int LAYER>
__global__ __launch_bounds__(512) void moe_gemm(
    const __hip_bfloat16* __restrict__ Abase,
    const __hip_bfloat16* __restrict__ Bbase,   // [E][N=1024][K=1024], K contiguous
    const float* __restrict__ bias,             // [E][1024]
    const int* __restrict__ rowmap,
    const int* __restrict__ counts,
    const float* __restrict__ gates,
    void* __restrict__ OutP)
{
    const int e = blockIdx.z;
    const int cnt = counts[e];
    const int m0 = blockIdx.y * 128;
    if (m0 >= cnt) return;
    const int n0 = blockIdx.x * 128;
    const int tid = threadIdx.x;
    const int lane = tid & 63;
    const int wave = tid >> 6;
    const int wm = (wave >> 2) * 64;   // wave's 64m x 32n quadrant
    const int wn = (wave & 3) * 32;
    const int lrow = lane & 15;
    const int quad = lane >> 4;

    __shared__ __hip_bfloat16 As[2][128 * 32];   // 16 KB (64B rows: conflict-free)
    __shared__ __hip_bfloat16 Bs[2][128 * 32];   // 16 KB

    // staging: 512 threads cover all 128 rows in one issue per operand per sub-buffer.
    // row = tid>>2 (0..127), 16B chunk = (tid&3)*8 elems; wave w covers rows 16w..16w+15
    // -> LDS dest = buf + w*1024 + lane*16 (wave-uniform base + lane*16 ✓)
    const int ar = m0 + (tid >> 2);
    const int ea = rowmap[e * CAP + (ar < cnt ? ar : 0)];
    const size_t srcA = (size_t)(LAYER == 1 ? (ea >> 1) : ea);
    const __hip_bfloat16* gA = Abase + srcA * DD + (tid & 3) * 8;
    const __hip_bfloat16* Bexp = Bbase + (size_t)e * DD * HH;
    const __hip_bfloat16* gB = Bexp + (size_t)(n0 + (tid >> 2)) * DD + (tid & 3) * 8;

    f32x4 acc[4][2];
#pragma unroll
    for (int i = 0; i < 4; ++i)
#pragma unroll
        for (int j = 0; j < 2; ++j) acc[i][j] = (f32x4){0.f, 0.f, 0.f, 0.f};

    for (int kt = 0; kt < DD / 64; ++kt) {
#pragma unroll
        for (int s = 0; s < 2; ++s) {
            const int ko = kt * 64 + s * 32;
            GLL16(gA + ko, (char*)&As[s][0] + wave * 1024);
            GLL16(gB + ko, (char*)&Bs[s][0] + wave * 1024);
        }
        __syncthreads();

#pragma unroll
        for (int s = 0; s < 2; ++s) {
            const bf16x8* Av = (const bf16x8*)&As[s][0];
            const bf16x8* Bv = (const bf16x8*)&Bs[s][0];
            bf16x8 af[4], bfr[2];
#pragma unroll
            for (int i = 0; i < 4; ++i)
                af[i] = Av[(wm + i * 16 + lrow) * 4 + quad];
#pragma unroll
            for (int i = 0; i < 2; ++i)
                bfr[i] = Bv[(wn + i * 16 + lrow) * 4 + quad];
#pragma unroll
            for (int mi = 0; mi < 4; ++mi)
#pragma unroll
                for (int ni = 0; ni < 2; ++ni)
                    acc[mi][ni] = __builtin_amdgcn_mfma_f32_16x16x32_bf16(
                        af[mi], bfr[ni], acc[mi][ni], 0, 0, 0);
        }
        __syncthreads();
    }

    // epilogue: C/D layout col = lane&15, row = quad*4 + reg (m89/m91 verified)
    if (LAYER == 1) {
        __hip_bfloat16* abuf = (__hip_bfloat16*)OutP;
#pragma unroll
        for (int mi = 0; mi < 4; ++mi) {
#pragma unroll
            for (int r = 0; r < 4; ++r) {
                const int mrow = wm + mi * 16 + quad * 4 + r;
                const int gm = m0 + mrow;
                if (gm < cnt) {
                    const int ent = rowmap[e * CAP + gm];
                    __hip_bfloat16* orow = abuf + (size_t)ent * HH + n0 + wn + lrow;
#pragma unroll
                    for (int ni = 0; ni < 2; ++ni) {
                        float v = acc[mi][ni][r] + bias[e * HH + n0 + wn + ni * 16 + lrow];
                        v = 0.5f * v * (1.f + erff(v * 0.70710678118654752f));  // exact GELU
                        orow[ni * 16] = __float2bfloat16(v);
                    }
                }
            }
        }
    } else {
        float* obuf = (float*)OutP;
#pragma unroll
        for (int mi = 0; mi < 4; ++mi) {
#pragma unroll
            for (int r = 0; r < 4; ++r) {
                const int mrow = wm + mi * 16 + quad * 4 + r;
                const int gm = m0 + mrow;
                if (gm < cnt) {
                    const int ent = rowmap[e * CAP + gm];
                    const float g = gates[ent];
                    float* orow = obuf + (size_t)ent * DD + n0 + wn + lrow;
#pragma unroll
                    for (int ni = 0; ni < 2; ++ni) {
                        float v = acc[mi][ni][r] + bias[e * DD + n0 + wn + ni * 16 + lrow];
                        orow[ni * 16] = v * g;
                    }
                }
            }
        }
    }
}

// ---------------- combine: y[t] = o[t,0] + o[t,1] ----------------
__global__ __launch_bounds__(256) void combine_kernel(
    const float* __restrict__ obuf, float* __restrict__ y)
{
    const size_t i = (size_t)blockIdx.x * 256 + threadIdx.x;
    const size_t t = i >> 8;
    const size_t c = i & 255;
    const float4* o0 = (const float4*)(obuf + t * 2 * DD);
    float4 a = o0[c];
    float4 b = o0[256 + c];
    float4 r;
    r.x = a.x + b.x; r.y = a.y + b.y; r.z = a.z + b.z; r.w = a.w + b.w;
    ((float4*)y)[i] = r;
}

extern "C" void kernel_launch(void* const* d_in, const int* in_sizes, int n_in,
                              void* d_out, int out_size, void* d_ws, size_t ws_size,
                              hipStream_t stream)
{
    const float* x  = (const float*)d_in[0];
    const float* w1 = (const float*)d_in[1];
    const float* b1 = (const float*)d_in[2];
    const float* w2 = (const float*)d_in[3];
    const float* b2 = (const float*)d_in[4];
    const float* wg = (const float*)d_in[5];
    float* y = (float*)d_out;

    char* ws = (char*)d_ws;
    __hip_bfloat16* xb   = (__hip_bfloat16*)(ws + OFF_XB);
    __hip_bfloat16* w1t  = (__hip_bfloat16*)(ws + OFF_W1T);
    __hip_bfloat16* w2t  = (__hip_bfloat16*)(ws + OFF_W2T);
    __hip_bfloat16* abuf = (__hip_bfloat16*)(ws + OFF_ABUF);
    float* obuf  = (float*)(ws + OFF_OBUF);
    int*   rowmap = (int*)(ws + OFF_ROWMAP);
    float* gates  = (float*)(ws + OFF_GATES);
    int*   counts = (int*)(ws + OFF_COUNTS);
    int*   picks  = (int*)(ws + OFF_PICKS);

    prep_kernel<<<NGATE + 4096, 256, 0, stream>>>(x, wg, w1, w2, xb, w1t, w2t, picks, gates);
    bucket_build<<<EE, 256, 0, stream>>>(picks, rowmap, counts);
    moe_gemm<1><<<dim3(HH / 128, CAP / 128, EE), 512, 0, stream>>>(
        xb, w1t, b1, rowmap, counts, gates, (void*)abuf);
    moe_gemm<2><<<dim3(DD / 128, CAP / 128, EE), 512, 0, stream>>>(
        abuf, w2t, b2, rowmap, counts, gates, (void*)obuf);
    combine_kernel<<<TT * DD / 4 / 256, 256, 0, stream>>>(obuf, y);
}

// Round 9
// 214.335 us; speedup vs baseline: 1.7301x; 1.0706x over previous
//
#include <hip/hip_runtime.h>
#include <hip/hip_bf16.h>
#include <math.h>

#define TT 4096
#define EE 8
#define DD 1024
#define HH 1024
#define CAP 4096

typedef __attribute__((ext_vector_type(8))) short bf16x8;
typedef __attribute__((ext_vector_type(4))) float f32x4;

// async global->LDS, 16B per lane; LDS dest is wave-uniform base + lane*16
#define GLL16(gp, lp)                                                                   \
    __builtin_amdgcn_global_load_lds((__attribute__((address_space(1))) void*)(gp),     \
                                     (__attribute__((address_space(3))) void*)(lp),     \
                                     16, 0, 0)

// ---------------- workspace layout (bytes) ----------------
static const size_t OFF_XB     = 0;                         // bf16 [4096][1024]  8 MB
static const size_t OFF_W1T    = 8u * 1024 * 1024;          // bf16 [8][H][D]    16 MB
static const size_t OFF_W2T    = 24u * 1024 * 1024;         // bf16 [8][D][H]    16 MB
static const size_t OFF_ABUF   = 40u * 1024 * 1024;         // bf16 [8192][1024] 16 MB
static const size_t OFF_OBUF   = 56u * 1024 * 1024;         // f32  [8192][1024] 32 MB
static const size_t OFF_ROWMAP = 88u * 1024 * 1024;         // int  [8][4096]   128 KB
static const size_t OFF_GATES  = OFF_ROWMAP + 8 * CAP * 4;  // f32  [8192]       32 KB
static const size_t OFF_COUNTS = OFF_GATES + 8192 * 4;      // int  [8]
static const size_t OFF_PICKS  = OFF_COUNTS + 256;          // int  [4096]       16 KB

#define NGATE 1024   // gate blocks come FIRST

// ---------------- prep: gating (blocks 0..1023, 1 token/wave) + transpose (1024..5119) --
__global__ __launch_bounds__(256) void prep_kernel(
    const float* __restrict__ x, const float* __restrict__ wg,
    const float* __restrict__ w1, const float* __restrict__ w2,
    __hip_bfloat16* __restrict__ xb,
    __hip_bfloat16* __restrict__ w1t, __hip_bfloat16* __restrict__ w2t,
    int* __restrict__ picks, float* __restrict__ gates)
{
    __shared__ float tl[64][65];
    const int bid = blockIdx.x;
    const int tid = threadIdx.x;

    if (bid >= NGATE) {
        // ---- transpose path: 16 matrices x 256 tiles of 64x64 ----
        const int bt = bid - NGATE;
        const int mat = bt >> 8;
        const int tt = bt & 255;
        const int R = (tt >> 4) * 64;   // src row base (k)
        const int C = (tt & 15) * 64;   // src col base (n)
        const float* src = (mat < EE ? w1 : w2) + (size_t)(mat & 7) * DD * HH;
        __hip_bfloat16* dst = (mat < EE ? w1t : w2t) + (size_t)(mat & 7) * DD * HH;

        const int lrow = tid >> 4;
        const int c4 = tid & 15;
#pragma unroll
        for (int i = 0; i < 4; ++i) {
            const int r = lrow + i * 16;
            float4 v = *(const float4*)(src + (size_t)(R + r) * 1024 + C + c4 * 4);
            tl[r][c4 * 4 + 0] = v.x;
            tl[r][c4 * 4 + 1] = v.y;
            tl[r][c4 * 4 + 2] = v.z;
            tl[r][c4 * 4 + 3] = v.w;
        }
        __syncthreads();
        const int seg = tid & 7;
        const int orow0 = tid >> 3;
#pragma unroll
        for (int p = 0; p < 2; ++p) {
            const int orow = orow0 + p * 32;
            unsigned short u[8];
#pragma unroll
            for (int j = 0; j < 8; ++j) {
                __hip_bfloat16 h = __float2bfloat16(tl[seg * 8 + j][orow]);
                u[j] = *(unsigned short*)&h;
            }
            *(ushort4*)(dst + (size_t)(C + orow) * 1024 + R + seg * 8)     = (ushort4){u[0], u[1], u[2], u[3]};
            *(ushort4*)(dst + (size_t)(C + orow) * 1024 + R + seg * 8 + 4) = (ushort4){u[4], u[5], u[6], u[7]};
        }
        return;
    }

    // ---- gate path: one token per wave ----
    const int lane = tid & 63;
    const int wave = tid >> 6;
    const int t = bid * 4 + wave;
    {
        const float4* xr = (const float4*)(x + (size_t)t * DD);
        ushort4* xbr = (ushort4*)(xb + (size_t)t * DD);

        float acc[EE];
#pragma unroll
        for (int e = 0; e < EE; ++e) acc[e] = 0.f;

#pragma unroll
        for (int c = 0; c < 4; ++c) {
            const int v4 = lane + 64 * c;
            float4 xv = xr[v4];
            __hip_bfloat16 h0 = __float2bfloat16(xv.x);
            __hip_bfloat16 h1 = __float2bfloat16(xv.y);
            __hip_bfloat16 h2 = __float2bfloat16(xv.z);
            __hip_bfloat16 h3 = __float2bfloat16(xv.w);
            ushort4 s;
            s.x = *(unsigned short*)&h0; s.y = *(unsigned short*)&h1;
            s.z = *(unsigned short*)&h2; s.w = *(unsigned short*)&h3;
            xbr[v4] = s;
            const float4* wrow = (const float4*)(wg + (size_t)(4 * v4) * EE);
            const float xs[4] = {xv.x, xv.y, xv.z, xv.w};
#pragma unroll
            for (int q = 0; q < 4; ++q) {
                float4 w0 = wrow[q * 2];
                float4 w1v = wrow[q * 2 + 1];
                acc[0] = fmaf(xs[q], w0.x, acc[0]);
                acc[1] = fmaf(xs[q], w0.y, acc[1]);
                acc[2] = fmaf(xs[q], w0.z, acc[2]);
                acc[3] = fmaf(xs[q], w0.w, acc[3]);
                acc[4] = fmaf(xs[q], w1v.x, acc[4]);
                acc[5] = fmaf(xs[q], w1v.y, acc[5]);
                acc[6] = fmaf(xs[q], w1v.z, acc[6]);
                acc[7] = fmaf(xs[q], w1v.w, acc[7]);
            }
        }
#pragma unroll
        for (int off = 32; off > 0; off >>= 1) {
#pragma unroll
            for (int e = 0; e < EE; ++e) acc[e] += __shfl_xor(acc[e], off, 64);
        }
        if (lane == 0) {
            float mx = acc[0];
#pragma unroll
            for (int e = 1; e < EE; ++e) mx = fmaxf(mx, acc[e]);
            float p[EE];
            float s = 0.f;
#pragma unroll
            for (int e = 0; e < EE; ++e) { p[e] = expf(acc[e] - mx); s += p[e]; }
            int i0 = 0;
#pragma unroll
            for (int e = 1; e < EE; ++e) if (acc[e] > acc[i0]) i0 = e;
            int i1 = (i0 == 0) ? 1 : 0;
#pragma unroll
            for (int e = 0; e < EE; ++e) {
                if (e != i0 && acc[e] > acc[i1]) i1 = e;
            }
            float v0 = p[i0] / s, v1 = p[i1] / s;
            float den = v0 + v1 + 1e-6f;
            gates[t * 2 + 0] = v0 / den;
            gates[t * 2 + 1] = v1 / den;
            picks[t] = i0 | (i1 << 4);
        }
    }
}

// ---------------- bucket build (deterministic, no global atomics) ----------------
__global__ __launch_bounds__(256) void bucket_build(
    const int* __restrict__ picks, int* __restrict__ rowmap, int* __restrict__ counts)
{
    const int e = blockIdx.x;
    const int tid = threadIdx.x;
    const int lane = tid & 63;
    const int wave = tid >> 6;
    __shared__ int wsum[4];

    int runtot = 0;
    for (int tb = 0; tb < TT; tb += 256) {
        const int t = tb + tid;
        const int p = picks[t];
        const int m0 = ((p & 15) == e) ? 1 : 0;
        const int m1 = (((p >> 4) & 15) == e) ? 1 : 0;
        const int c = m0 + m1;
        int incl = c;
#pragma unroll
        for (int off = 1; off < 64; off <<= 1) {
            int v = __shfl_up(incl, off, 64);
            if (lane >= off) incl += v;
        }
        if (lane == 63) wsum[wave] = incl;
        __syncthreads();
        int wbase = 0;
#pragma unroll
        for (int w = 0; w < 4; ++w) wbase += (w < wave) ? wsum[w] : 0;
        int slot = runtot + wbase + incl - c;
        if (m0) { rowmap[e * CAP + slot] = t * 2; slot += 1; }
        if (m1) { rowmap[e * CAP + slot] = t * 2 + 1; }
        runtot += wsum[0] + wsum[1] + wsum[2] + wsum[3];
        __syncthreads();
    }
    if (tid == 0) counts[e] = runtot;
}

// ---------------- grouped GEMM: 128x128, 512 thr, BK=64, XCD-pinned experts ------------
// r8 structure (traffic-optimal tile + 16 waves/CU) was fill-traffic-bound: FETCH
// 75.5 MB because same-expert blocks spread over 8 non-shared XCD L2s each pull a
// copy of the expert's ~4MB working set. 1D grid + `e = id & 7` pins expert e's
// blocks to XCD e (round-robin dispatch heuristic; speed-only, correctness-safe):
// one L2 then holds that expert's whole A+B working set.
// LAYER==1: out = gelu(C + b1) -> bf16 abuf[(t,k) slot]
// LAYER==2: out = (C + b2) * gate -> f32 obuf[(t,k) slot]
template <int LAYER>
__global__ __launch_bounds__(512) void moe_gemm(
    const __hip_bfloat16* __restrict__ Abase,
    const __hip_bfloat16* __restrict__ Bbase,   // [E][N=1024][K=1024], K contiguous
    const float* __restrict__ bias,             // [E][1024]
    const int* __restrict__ rowmap,
    const int* __restrict__ counts,
    const float* __restrict__ gates,
    void* __restrict__ OutP)
{
    // decode: e = XCD selector (fastest), then n, then m (so live blocks dispatch first)
    const int bid = blockIdx.x;
    const int e = bid & 7;
    const int n0 = ((bid >> 3) & 7) * 128;
    const int m0 = (bid >> 6) * 128;
    const int cnt = counts[e];
    if (m0 >= cnt) return;
    const int tid = threadIdx.x;
    const int lane = tid & 63;
    const int wave = tid >> 6;
    const int wm = (wave >> 2) * 64;   // wave's 64m x 32n quadrant
    const int wn = (wave & 3) * 32;
    const int lrow = lane & 15;
    const int quad = lane >> 4;

    __shared__ __hip_bfloat16 As[2][128 * 32];   // 16 KB (64B rows: conflict-free)
    __shared__ __hip_bfloat16 Bs[2][128 * 32];   // 16 KB

    // staging: row = tid>>2 (0..127), 16B chunk = (tid&3)*8 elems; wave w covers rows
    // 16w..16w+15 -> LDS dest = buf + w*1024 + lane*16 (wave-uniform base + lane*16)
    const int ar = m0 + (tid >> 2);
    const int ea = rowmap[e * CAP + (ar < cnt ? ar : 0)];
    const size_t srcA = (size_t)(LAYER == 1 ? (ea >> 1) : ea);
    const __hip_bfloat16* gA = Abase + srcA * DD + (tid & 3) * 8;
    const __hip_bfloat16* Bexp = Bbase + (size_t)e * DD * HH;
    const __hip_bfloat16* gB = Bexp + (size_t)(n0 + (tid >> 2)) * DD + (tid & 3) * 8;

    f32x4 acc[4][2];
#pragma unroll
    for (int i = 0; i < 4; ++i)
#pragma unroll
        for (int j = 0; j < 2; ++j) acc[i][j] = (f32x4){0.f, 0.f, 0.f, 0.f};

    for (int kt = 0; kt < DD / 64; ++kt) {
#pragma unroll
        for (int s = 0; s < 2; ++s) {
            const int ko = kt * 64 + s * 32;
            GLL16(gA + ko, (char*)&As[s][0] + wave * 1024);
            GLL16(gB + ko, (char*)&Bs[s][0] + wave * 1024);
        }
        __syncthreads();

#pragma unroll
        for (int s = 0; s < 2; ++s) {
            const bf16x8* Av = (const bf16x8*)&As[s][0];
            const bf16x8* Bv = (const bf16x8*)&Bs[s][0];
            bf16x8 af[4], bfr[2];
#pragma unroll
            for (int i = 0; i < 4; ++i)
                af[i] = Av[(wm + i * 16 + lrow) * 4 + quad];
#pragma unroll
            for (int i = 0; i < 2; ++i)
                bfr[i] = Bv[(wn + i * 16 + lrow) * 4 + quad];
#pragma unroll
            for (int mi = 0; mi < 4; ++mi)
#pragma unroll
                for (int ni = 0; ni < 2; ++ni)
                    acc[mi][ni] = __builtin_amdgcn_mfma_f32_16x16x32_bf16(
                        af[mi], bfr[ni], acc[mi][ni], 0, 0, 0);
        }
        __syncthreads();
    }

    // epilogue: C/D layout col = lane&15, row = quad*4 + reg (m89/m91 verified)
    if (LAYER == 1) {
        __hip_bfloat16* abuf = (__hip_bfloat16*)OutP;
#pragma unroll
        for (int mi = 0; mi < 4; ++mi) {
#pragma unroll
            for (int r = 0; r < 4; ++r) {
                const int mrow = wm + mi * 16 + quad * 4 + r;
                const int gm = m0 + mrow;
                if (gm < cnt) {
                    const int ent = rowmap[e * CAP + gm];
                    __hip_bfloat16* orow = abuf + (size_t)ent * HH + n0 + wn + lrow;
#pragma unroll
                    for (int ni = 0; ni < 2; ++ni) {
                        float v = acc[mi][ni][r] + bias[e * HH + n0 + wn + ni * 16 + lrow];
                        v = 0.5f * v * (1.f + erff(v * 0.70710678118654752f));  // exact GELU
                        orow[ni * 16] = __float2bfloat16(v);
                    }
                }
            }
        }
    } else {
        float* obuf = (float*)OutP;
#pragma unroll
        for (int mi = 0; mi < 4; ++mi) {
#pragma unroll
            for (int r = 0; r < 4; ++r) {
                const int mrow = wm + mi * 16 + quad * 4 + r;
                const int gm = m0 + mrow;
                if (gm < cnt) {
                    const int ent = rowmap[e * CAP + gm];
                    const float g = gates[ent];
                    float* orow = obuf + (size_t)ent * DD + n0 + wn + lrow;
#pragma unroll
                    for (int ni = 0; ni < 2; ++ni) {
                        float v = acc[mi][ni][r] + bias[e * DD + n0 + wn + ni * 16 + lrow];
                        orow[ni * 16] = v * g;
                    }
                }
            }
        }
    }
}

// ---------------- combine: y[t] = o[t,0] + o[t,1] ----------------
__global__ __launch_bounds__(256) void combine_kernel(
    const float* __restrict__ obuf, float* __restrict__ y)
{
    const size_t i = (size_t)blockIdx.x * 256 + threadIdx.x;
    const size_t t = i >> 8;
    const size_t c = i & 255;
    const float4* o0 = (const float4*)(obuf + t * 2 * DD);
    float4 a = o0[c];
    float4 b = o0[256 + c];
    float4 r;
    r.x = a.x + b.x; r.y = a.y + b.y; r.z = a.z + b.z; r.w = a.w + b.w;
    ((float4*)y)[i] = r;
}

extern "C" void kernel_launch(void* const* d_in, const int* in_sizes, int n_in,
                              void* d_out, int out_size, void* d_ws, size_t ws_size,
                              hipStream_t stream)
{
    const float* x  = (const float*)d_in[0];
    const float* w1 = (const float*)d_in[1];
    const float* b1 = (const float*)d_in[2];
    const float* w2 = (const float*)d_in[3];
    const float* b2 = (const float*)d_in[4];
    const float* wg = (const float*)d_in[5];
    float* y = (float*)d_out;

    char* ws = (char*)d_ws;
    __hip_bfloat16* xb   = (__hip_bfloat16*)(ws + OFF_XB);
    __hip_bfloat16* w1t  = (__hip_bfloat16*)(ws + OFF_W1T);
    __hip_bfloat16* w2t  = (__hip_bfloat16*)(ws + OFF_W2T);
    __hip_bfloat16* abuf = (__hip_bfloat16*)(ws + OFF_ABUF);
    float* obuf  = (float*)(ws + OFF_OBUF);
    int*   rowmap = (int*)(ws + OFF_ROWMAP);
    float* gates  = (float*)(ws + OFF_GATES);
    int*   counts = (int*)(ws + OFF_COUNTS);
    int*   picks  = (int*)(ws + OFF_PICKS);

    prep_kernel<<<NGATE + 4096, 256, 0, stream>>>(x, wg, w1, w2, xb, w1t, w2t, picks, gates);
    bucket_build<<<EE, 256, 0, stream>>>(picks, rowmap, counts);
    // 1D grid: id = (m<<6) | (n<<3) | e  -> 8 experts x 8 n x 32 m-capacity
    moe_gemm<1><<<(CAP / 128) * 8 * EE, 512, 0, stream>>>(
        xb, w1t, b1, rowmap, counts, gates, (void*)abuf);
    moe_gemm<2><<<(CAP / 128) * 8 * EE, 512, 0, stream>>>(
        abuf, w2t, b2, rowmap, counts, gates, (void*)obuf);
    combine_kernel<<<TT * DD / 4 / 256, 256, 0, stream>>>(obuf, y);
}